// Round 1
// baseline (3778.737 us; speedup 1.0000x reference)
//
#include <hip/hip_runtime.h>
#include <cstddef>

#define BB 8
#define CCH 256
#define HH 64
#define WW 64
#define NPIX 4096   // H*W
#define MPOOL 1024  // (H/2)*(W/2)
#define DD 32       // C/8
#define DVV 128     // C/2

// ---------------- theta = conv1x1(x, theta_w, theta_b), stored (n, i, d) ----------------
__global__ __launch_bounds__(256) void theta_k(const float* __restrict__ x,
    const float* __restrict__ w, const float* __restrict__ b, float* __restrict__ theta)
{
    int idx = blockIdx.x * 256 + threadIdx.x;          // n*N*D + i*D + d
    int d = idx & (DD - 1);
    int i = (idx >> 5) & (NPIX - 1);
    int n = idx >> 17;                                 // N*D = 131072 = 2^17
    const float* xp = x + ((size_t)n * CCH) * NPIX + i;
    const float* wp = w + d * CCH;
    float acc = b[d];
    #pragma unroll 8
    for (int c = 0; c < CCH; ++c) acc = fmaf(wp[c], xp[(size_t)c * NPIX], acc);
    theta[idx] = acc;
}

// ---------------- phi = maxpool2(conv1x1(x, phi_w, phi_b)), stored TRANSPOSED (n, j, d) ----
__global__ __launch_bounds__(256) void phi_k(const float* __restrict__ x,
    const float* __restrict__ w, const float* __restrict__ b, float* __restrict__ phi_t)
{
    int idx = blockIdx.x * 256 + threadIdx.x;          // n*M*D + j*D + d
    int d = idx & (DD - 1);
    int j = (idx >> 5) & (MPOOL - 1);
    int n = idx >> 15;                                 // M*D = 32768 = 2^15
    int ph = j >> 5, pw = j & 31;
    const float* wp = w + d * CCH;
    float bias = b[d];
    float m = -1e30f;
    #pragma unroll
    for (int dy = 0; dy < 2; ++dy)
    #pragma unroll
    for (int dx = 0; dx < 2; ++dx) {
        int pix = (2 * ph + dy) * WW + 2 * pw + dx;
        const float* xp = x + ((size_t)n * CCH) * NPIX + pix;
        float acc = bias;
        #pragma unroll 8
        for (int c = 0; c < CCH; ++c) acc = fmaf(wp[c], xp[(size_t)c * NPIX], acc);
        m = fmaxf(m, acc);
    }
    phi_t[idx] = m;
}

// ---------------- g = maxpool2(conv1x1(x, g_w, g_b)), stored (n, c, j) ----------------
__global__ __launch_bounds__(256) void g_k(const float* __restrict__ x,
    const float* __restrict__ w, const float* __restrict__ b, float* __restrict__ gbuf)
{
    int idx = blockIdx.x * 256 + threadIdx.x;          // n*DV*M + c*M + j
    int j = idx & (MPOOL - 1);
    int c = (idx >> 10) & (DVV - 1);
    int n = idx >> 17;                                 // DV*M = 131072 = 2^17
    int ph = j >> 5, pw = j & 31;
    const float* wp = w + c * CCH;
    float bias = b[c];
    float m = -1e30f;
    #pragma unroll
    for (int dy = 0; dy < 2; ++dy)
    #pragma unroll
    for (int dx = 0; dx < 2; ++dx) {
        int pix = (2 * ph + dy) * WW + 2 * pw + dx;
        const float* xp = x + ((size_t)n * CCH) * NPIX + pix;
        float acc = bias;
        #pragma unroll 8
        for (int cc = 0; cc < CCH; ++cc) acc = fmaf(wp[cc], xp[(size_t)cc * NPIX], acc);
        m = fmaxf(m, acc);
    }
    gbuf[idx] = m;
}

// ---------------- fused energy -> softmax -> PV, one block per (n, i) row ----------------
// att_out stored (n, i, c) contiguous in c.
__global__ __launch_bounds__(256) void attn_k(const float* __restrict__ theta,
    const float* __restrict__ phi_t, const float* __restrict__ gbuf,
    float* __restrict__ att_out)
{
    int blk = blockIdx.x;                              // n*N + i
    int n = blk >> 12;
    int i = blk & (NPIX - 1);
    int t = threadIdx.x;

    __shared__ float th[DD];
    __shared__ float e[MPOOL];
    __shared__ float wred[4];
    __shared__ float sbc;

    if (t < DD) th[t] = theta[((size_t)n * NPIX + i) * DD + t];
    __syncthreads();

    // energies: each thread computes 4 of the 1024 columns
    float ev[4];
    float lmax = -1e30f;
    #pragma unroll
    for (int r = 0; r < 4; ++r) {
        int j = t + r * 256;
        const float* pp = phi_t + ((size_t)n * MPOOL + j) * DD;
        float acc = 0.f;
        #pragma unroll
        for (int d = 0; d < DD; ++d) acc = fmaf(th[d], pp[d], acc);
        ev[r] = acc;
        lmax = fmaxf(lmax, acc);
    }
    // block-reduce max
    #pragma unroll
    for (int off = 32; off > 0; off >>= 1) lmax = fmaxf(lmax, __shfl_down(lmax, off));
    if ((t & 63) == 0) wred[t >> 6] = lmax;
    __syncthreads();
    if (t == 0) sbc = fmaxf(fmaxf(wred[0], wred[1]), fmaxf(wred[2], wred[3]));
    __syncthreads();
    float gmax = sbc;

    // exp + block-reduce sum
    float lsum = 0.f;
    #pragma unroll
    for (int r = 0; r < 4; ++r) {
        float v = __expf(ev[r] - gmax);
        e[t + r * 256] = v;
        lsum += v;
    }
    #pragma unroll
    for (int off = 32; off > 0; off >>= 1) lsum += __shfl_down(lsum, off);
    if ((t & 63) == 0) wred[t >> 6] = lsum;
    __syncthreads();
    if (t == 0) sbc = wred[0] + wred[1] + wred[2] + wred[3];
    __syncthreads();
    float inv = 1.f / sbc;

    // PV: threads 0..127 each own one value-channel c, dot over 1024 contiguous floats
    if (t < DVV) {
        const float* gp = gbuf + ((size_t)n * DVV + t) * MPOOL;
        float a0 = 0.f, a1 = 0.f, a2 = 0.f, a3 = 0.f;
        for (int j = 0; j < MPOOL; j += 4) {
            a0 = fmaf(e[j + 0], gp[j + 0], a0);
            a1 = fmaf(e[j + 1], gp[j + 1], a1);
            a2 = fmaf(e[j + 2], gp[j + 2], a2);
            a3 = fmaf(e[j + 3], gp[j + 3], a3);
        }
        att_out[((size_t)n * NPIX + i) * DVV + t] = (a0 + a1 + a2 + a3) * inv;
    }
}

// ---------------- final conv1x1 + gamma*out + x ----------------
__global__ __launch_bounds__(256) void out_k(const float* __restrict__ att_out,
    const float* __restrict__ w, const float* __restrict__ b,
    const float* __restrict__ x, const float* __restrict__ gamma,
    float* __restrict__ out)
{
    int idx = blockIdx.x * 256 + threadIdx.x;          // n*C*N + o*N + i
    int i = idx & (NPIX - 1);
    int o = (idx >> 12) & (CCH - 1);
    int n = idx >> 20;                                 // C*N = 2^20
    const float* ap = att_out + ((size_t)n * NPIX + i) * DVV;
    const float* wp = w + o * DVV;
    float acc = b[o];
    #pragma unroll 8
    for (int c = 0; c < DVV; ++c) acc = fmaf(wp[c], ap[c], acc);
    out[idx] = gamma[0] * acc + x[idx];
}

extern "C" void kernel_launch(void* const* d_in, const int* in_sizes, int n_in,
                              void* d_out, int out_size, void* d_ws, size_t ws_size,
                              hipStream_t stream) {
    const float* x       = (const float*)d_in[0];
    const float* theta_w = (const float*)d_in[1];
    const float* theta_b = (const float*)d_in[2];
    const float* phi_w   = (const float*)d_in[3];
    const float* phi_b   = (const float*)d_in[4];
    const float* g_w     = (const float*)d_in[5];
    const float* g_b     = (const float*)d_in[6];
    const float* out_w   = (const float*)d_in[7];
    const float* out_b   = (const float*)d_in[8];
    const float* gamma   = (const float*)d_in[9];
    float* out = (float*)d_out;

    float* ws      = (float*)d_ws;
    float* theta   = ws;                  // 8*4096*32   = 1,048,576 floats
    float* phi_t   = ws + 1048576;        // 8*1024*32   =   262,144 floats
    float* gbuf    = ws + 1310720;        // 8*128*1024  = 1,048,576 floats
    float* att_out = ws + 2359296;        // 8*4096*128  = 4,194,304 floats
                                          // total 6,553,600 floats = 26.2 MB

    theta_k<<<4096, 256, 0, stream>>>(x, theta_w, theta_b, theta);
    phi_k<<<1024, 256, 0, stream>>>(x, phi_w, phi_b, phi_t);
    g_k<<<4096, 256, 0, stream>>>(x, g_w, g_b, gbuf);
    attn_k<<<32768, 256, 0, stream>>>(theta, phi_t, gbuf, att_out);
    out_k<<<32768, 256, 0, stream>>>(att_out, out_w, out_b, x, gamma, out);
}

// Round 2
// 632.509 us; speedup vs baseline: 5.9742x; 5.9742x over previous
//
#include <hip/hip_runtime.h>
#include <cstddef>

typedef __attribute__((ext_vector_type(8))) short short8;
typedef __attribute__((ext_vector_type(4))) float f32x4;

__device__ __forceinline__ unsigned short f2bf(float f) {
    union { float f; unsigned int u; } v; v.f = f;
    unsigned int r = v.u + 0x7fffu + ((v.u >> 16) & 1u);   // RNE
    return (unsigned short)(r >> 16);
}
__device__ __forceinline__ float bf2f(unsigned short u) {
    union { unsigned int u; float f; } v; v.u = ((unsigned int)u) << 16;
    return v.f;
}

// ---------- conv1x1, 32 output channels per thread, thread = pixel ----------
// x: (n, 256, 4096) fp32.  out: (n, pix, ostride) bf16, slice s writes [s*32, s*32+32).
__global__ __launch_bounds__(256) void conv32_k(const float* __restrict__ x,
    const float* __restrict__ w, const float* __restrict__ b,
    unsigned short* __restrict__ outb, int ostride)
{
    int gt = blockIdx.x * 256 + threadIdx.x;          // n*4096 + pix
    int s = blockIdx.y;
    const float* wp = w + s * 32 * 256;
    const float* bp = b + s * 32;
    const float* xp = x + ((size_t)(gt >> 12) * 256) * 4096 + (gt & 4095);
    float acc[32];
    #pragma unroll
    for (int o = 0; o < 32; ++o) acc[o] = 0.f;
    for (int c = 0; c < 256; c += 8) {
        float xv[8];
        #pragma unroll
        for (int u = 0; u < 8; ++u) xv[u] = xp[(size_t)(c + u) * 4096];
        #pragma unroll
        for (int o = 0; o < 32; ++o) {
            #pragma unroll
            for (int u = 0; u < 8; ++u)
                acc[o] = fmaf(wp[o * 256 + c + u], xv[u], acc[o]);
        }
    }
    unsigned short* op = outb + (size_t)gt * ostride + s * 32;
    #pragma unroll
    for (int o = 0; o < 32; ++o) op[o] = f2bf(acc[o] + bp[o]);
}

// ---------- maxpool for phi: (n,pix,32) bf16 -> (n,j,32) bf16 ----------
__global__ __launch_bounds__(256) void pool_qk_k(const unsigned short* __restrict__ pc,
    unsigned short* __restrict__ pt)
{
    int t = blockIdx.x * 256 + threadIdx.x;           // 8*1024*32 = 262144
    int d = t & 31;
    int j = (t >> 5) & 1023;
    int n = t >> 15;
    int p00 = ((j >> 5) * 2) * 64 + (j & 31) * 2;
    const unsigned short* base = pc + (((size_t)n << 12)) * 32;
    float a = bf2f(base[(size_t)p00 * 32 + d]);
    float b = bf2f(base[(size_t)(p00 + 1) * 32 + d]);
    float c = bf2f(base[(size_t)(p00 + 64) * 32 + d]);
    float e = bf2f(base[(size_t)(p00 + 65) * 32 + d]);
    pt[t] = f2bf(fmaxf(fmaxf(a, b), fmaxf(c, e)));
}

// ---------- maxpool + transpose for g: (n,pix,128) bf16 -> (n,c,j) bf16 ----------
__global__ __launch_bounds__(256) void pool_g_k(const unsigned short* __restrict__ gc,
    unsigned short* __restrict__ gt_)
{
    __shared__ unsigned short gl[128 * 66];
    int n = blockIdx.x >> 4;
    int j0 = (blockIdx.x & 15) * 64;
    int t = threadIdx.x;
    const unsigned short* base = gc + (((size_t)n << 12)) * 128;
    for (int ii = t; ii < 8192; ii += 256) {
        int c = ii & 127, jl = ii >> 7;
        int j = j0 + jl;
        int p00 = (j >> 5) * 128 + (j & 31) * 2;
        float a = bf2f(base[(size_t)p00 * 128 + c]);
        float b = bf2f(base[(size_t)(p00 + 1) * 128 + c]);
        float cc = bf2f(base[(size_t)(p00 + 64) * 128 + c]);
        float d = bf2f(base[(size_t)(p00 + 65) * 128 + c]);
        gl[c * 66 + jl] = f2bf(fmaxf(fmaxf(a, b), fmaxf(cc, d)));
    }
    __syncthreads();
    for (int ii = t; ii < 8192; ii += 256) {
        int jl = ii & 63, c = ii >> 6;
        gt_[(((size_t)n * 128 + c) << 10) + j0 + jl] = gl[c * 66 + jl];
    }
}

// ---------- fused attention: E=theta*phi^T (MFMA) -> exp -> P (LDS, bf16, swizzled)
// ----------                  -> out = P*g^T (MFMA) -> normalize -> att_t (n,c,i) bf16
__global__ __launch_bounds__(128) void attn_k(const unsigned short* __restrict__ theta,
    const unsigned short* __restrict__ phi_t, const unsigned short* __restrict__ g_t,
    unsigned short* __restrict__ att_t)
{
    __shared__ __align__(16) unsigned short P[32 * 1024];   // 64 KB
    int n = blockIdx.x >> 7;
    int i0 = (blockIdx.x & 127) * 32;
    int t = threadIdx.x;
    int wv = t >> 6;                 // wave 0/1 -> rows [wv*16, wv*16+16)
    int l = t & 63;
    int lg = l >> 4;                 // k-group 0..3
    int ll = l & 15;                 // m/n index within fragment
    int riA = wv * 16 + ll;          // A-operand row (theta / P row)
    int rowD = wv * 16 + lg * 4;     // D-layout base row

    short8 afrag = *(const short8*)(theta + ((size_t)(n * 4096 + i0 + riA)) * 32 + lg * 8);

    const f32x4 zero = {0.f, 0.f, 0.f, 0.f};
    float rowsum[4] = {0.f, 0.f, 0.f, 0.f};
    #pragma unroll 2
    for (int jt = 0; jt < 64; ++jt) {
        int j0 = jt * 16;
        short8 bfrag = *(const short8*)(phi_t + ((size_t)(n * 1024 + j0 + ll)) * 32 + lg * 8);
        f32x4 e = __builtin_amdgcn_mfma_f32_16x16x32_bf16(afrag, bfrag, zero, 0, 0, 0);
        int col = j0 + ll;
        #pragma unroll
        for (int r = 0; r < 4; ++r) {
            float p = __expf(e[r]);              // no max-subtract: |E| << 88
            rowsum[r] += p;
            int row = rowD + r;
            P[row * 1024 + (col ^ ((row & 7) << 3))] = f2bf(p);
        }
    }
    #pragma unroll
    for (int r = 0; r < 4; ++r) {
        #pragma unroll
        for (int off = 1; off < 16; off <<= 1)
            rowsum[r] += __shfl_xor(rowsum[r], off);
    }
    float inv[4];
    #pragma unroll
    for (int r = 0; r < 4; ++r) inv[r] = 1.f / rowsum[r];

    f32x4 acc[8];
    #pragma unroll
    for (int ct = 0; ct < 8; ++ct) acc[ct] = zero;

    #pragma unroll 2
    for (int kt = 0; kt < 32; ++kt) {
        int jb = kt * 32 + lg * 8;
        short8 pa = *(const short8*)&P[riA * 1024 + (jb ^ ((riA & 7) << 3))];
        const unsigned short* gb_base = g_t + ((size_t)(n * 128)) * 1024 + jb;
        #pragma unroll
        for (int ct = 0; ct < 8; ++ct) {
            short8 gb = *(const short8*)(gb_base + (size_t)(ct * 16 + ll) * 1024);
            acc[ct] = __builtin_amdgcn_mfma_f32_16x16x32_bf16(pa, gb, acc[ct], 0, 0, 0);
        }
    }
    __syncthreads();
    float* A = (float*)P;            // reuse as [128][33] fp32 (17 KB)
    #pragma unroll
    for (int ct = 0; ct < 8; ++ct) {
        int c = ct * 16 + ll;
        #pragma unroll
        for (int r = 0; r < 4; ++r)
            A[c * 33 + rowD + r] = acc[ct][r] * inv[r];
    }
    __syncthreads();
    for (int ii = t; ii < 4096; ii += 128) {
        int c = ii >> 5, il = ii & 31;
        att_t[((size_t)(n * 128 + c)) * 4096 + i0 + il] = f2bf(A[c * 33 + il]);
    }
}

// ---------- final conv1x1 (256 <- 128) + gamma*out + x, thread = pixel ----------
__global__ __launch_bounds__(256) void out_k(const unsigned short* __restrict__ att_t,
    const float* __restrict__ w, const float* __restrict__ b,
    const float* __restrict__ x, const float* __restrict__ gamma,
    float* __restrict__ out)
{
    int gt = blockIdx.x * 256 + threadIdx.x;
    int pix = gt & 4095, n = gt >> 12;
    int o0 = blockIdx.y * 64;
    const unsigned short* ap = att_t + ((size_t)(n * 128)) * 4096 + pix;
    float acc[64];
    #pragma unroll
    for (int o = 0; o < 64; ++o) acc[o] = 0.f;
    for (int c = 0; c < 128; c += 4) {
        float av[4];
        #pragma unroll
        for (int u = 0; u < 4; ++u) av[u] = bf2f(ap[(size_t)(c + u) * 4096]);
        #pragma unroll
        for (int o = 0; o < 64; ++o) {
            #pragma unroll
            for (int u = 0; u < 4; ++u)
                acc[o] = fmaf(w[(o0 + o) * 128 + c + u], av[u], acc[o]);
        }
    }
    float gm = gamma[0];
    #pragma unroll
    for (int o = 0; o < 64; ++o) {
        size_t oi = ((size_t)(n * 256 + o0 + o)) * 4096 + pix;
        out[oi] = fmaf(gm, acc[o] + b[o0 + o], x[oi]);
    }
}

extern "C" void kernel_launch(void* const* d_in, const int* in_sizes, int n_in,
                              void* d_out, int out_size, void* d_ws, size_t ws_size,
                              hipStream_t stream) {
    const float* x       = (const float*)d_in[0];
    const float* theta_w = (const float*)d_in[1];
    const float* theta_b = (const float*)d_in[2];
    const float* phi_w   = (const float*)d_in[3];
    const float* phi_b   = (const float*)d_in[4];
    const float* g_w     = (const float*)d_in[5];
    const float* g_b     = (const float*)d_in[6];
    const float* out_w   = (const float*)d_in[7];
    const float* out_b   = (const float*)d_in[8];
    const float* gamma   = (const float*)d_in[9];
    float* out = (float*)d_out;

    char* w8 = (char*)d_ws;
    unsigned short* theta_buf = (unsigned short*)(w8);              // 8*4096*32*2  = 2 MB
    unsigned short* phiconv   = (unsigned short*)(w8 + 2097152);    // 2 MB
    unsigned short* phi_tb    = (unsigned short*)(w8 + 4194304);    // 8*1024*32*2  = 512 KB
    unsigned short* gconv     = (unsigned short*)(w8 + 4718592);    // 8*4096*128*2 = 8 MB
    unsigned short* g_tb      = (unsigned short*)(w8 + 13107200);   // 8*128*1024*2 = 2 MB
    unsigned short* att_tb    = (unsigned short*)(w8 + 15204352);   // 8*128*4096*2 = 8 MB
                                                                    // total 23.6 MB

    conv32_k<<<dim3(128, 1), 256, 0, stream>>>(x, theta_w, theta_b, theta_buf, 32);
    conv32_k<<<dim3(128, 1), 256, 0, stream>>>(x, phi_w, phi_b, phiconv, 32);
    conv32_k<<<dim3(128, 4), 256, 0, stream>>>(x, g_w, g_b, gconv, 128);
    pool_qk_k<<<1024, 256, 0, stream>>>(phiconv, phi_tb);
    pool_g_k<<<128, 256, 0, stream>>>(gconv, g_tb);
    attn_k<<<1024, 128, 0, stream>>>(theta_buf, phi_tb, g_tb, att_tb);
    out_k<<<dim3(128, 4), 256, 0, stream>>>(att_tb, out_w, out_b, x, gamma, out);
}

// Round 3
// 230.526 us; speedup vs baseline: 16.3918x; 2.7438x over previous
//
#include <hip/hip_runtime.h>
#include <cstddef>

typedef __attribute__((ext_vector_type(8))) short short8;
typedef __attribute__((ext_vector_type(4))) float f32x4;

__device__ __forceinline__ unsigned short f2bf(float f) {
    union { float f; unsigned int u; } v; v.f = f;
    unsigned int r = v.u + 0x7fffu + ((v.u >> 16) & 1u);   // RNE
    return (unsigned short)(r >> 16);
}
__device__ __forceinline__ float bf2f(unsigned short u) {
    union { unsigned int u; float f; } v; v.u = ((unsigned int)u) << 16;
    return v.f;
}

// ---------- x (n,c,pix) fp32 -> xb_t (n,pix,c) bf16, LDS tile transpose ----------
__global__ __launch_bounds__(256) void xt_k(const float* __restrict__ x,
                                            unsigned short* __restrict__ xb_t)
{
    __shared__ float T[64][65];
    int p0 = blockIdx.x * 64;
    int c0 = blockIdx.y * 64;
    int n  = blockIdx.z;
    int t = threadIdx.x;
    int r4 = t >> 6;         // 0..3
    int col = t & 63;
    const float* xp = x + ((size_t)(n * 256 + c0)) * 4096 + p0;
    #pragma unroll
    for (int it = 0; it < 16; ++it) {
        int c = it * 4 + r4;
        T[c][col] = xp[(size_t)c * 4096 + col];
    }
    __syncthreads();
    unsigned short* op = xb_t + ((size_t)(n * 4096 + p0)) * 256 + c0;
    #pragma unroll
    for (int it = 0; it < 16; ++it) {
        int p = it * 4 + r4;
        op[(size_t)p * 256 + col] = f2bf(T[col][p]);
    }
}

// ---------- weights/bias -> bf16 concat ----------
__global__ __launch_bounds__(256) void cvt_k(const float* __restrict__ tw,
    const float* __restrict__ tb, const float* __restrict__ pw, const float* __restrict__ pb,
    const float* __restrict__ gw, const float* __restrict__ gb, const float* __restrict__ ow,
    unsigned short* __restrict__ wb, unsigned short* __restrict__ owb, float* __restrict__ bcat)
{
    int idx = blockIdx.x * 256 + threadIdx.x;
    if (idx < 49152) {
        int o = idx >> 8, c = idx & 255;
        float v = (o < 32) ? tw[o * 256 + c] : (o < 64) ? pw[(o - 32) * 256 + c]
                                             : gw[(o - 64) * 256 + c];
        wb[idx] = f2bf(v);
    } else if (idx < 81920) {
        owb[idx - 49152] = f2bf(ow[idx - 49152]);
    } else if (idx < 82112) {
        int o = idx - 81920;
        bcat[o] = (o < 32) ? tb[o] : (o < 64) ? pb[o - 32] : gb[o - 64];
    }
}

// ---------- fused QKV conv GEMM + maxpool epilogue ----------
// M=192 (theta 0..31, phi 32..63, g 64..191), N=128 pixels (image row-pair rp), K=256.
// theta (n,i,32); phi_t (n,j,32); g_t (n,c,1024): all bf16.
__global__ __launch_bounds__(256) void conv_qkv_k(const unsigned short* __restrict__ xb_t,
    const unsigned short* __restrict__ wb, const float* __restrict__ bcat,
    unsigned short* __restrict__ theta, unsigned short* __restrict__ phi_t,
    unsigned short* __restrict__ g_t)
{
    int rp = blockIdx.x;            // 0..31 row-pair
    int n  = blockIdx.y;
    int t = threadIdx.x;
    int w = t >> 6;
    int l = t & 63;
    int lg = l >> 4, ll = l & 15;

    const unsigned short* xbase = xb_t + ((size_t)(n * 4096 + rp * 128)) * 256;
    const f32x4 zero = {0.f, 0.f, 0.f, 0.f};
    f32x4 acc[3][8];
    #pragma unroll
    for (int mt = 0; mt < 3; ++mt)
        #pragma unroll
        for (int nt = 0; nt < 8; ++nt) acc[mt][nt] = zero;

    for (int kk = 0; kk < 8; ++kk) {
        int ko = kk * 32 + lg * 8;
        short8 af[3];
        #pragma unroll
        for (int mt = 0; mt < 3; ++mt)
            af[mt] = *(const short8*)(wb + (size_t)(w * 48 + mt * 16 + ll) * 256 + ko);
        #pragma unroll
        for (int nt = 0; nt < 8; ++nt) {
            short8 bf = *(const short8*)(xbase + (size_t)(nt * 16 + ll) * 256 + ko);
            #pragma unroll
            for (int mt = 0; mt < 3; ++mt)
                acc[mt][nt] = __builtin_amdgcn_mfma_f32_16x16x32_bf16(af[mt], bf, acc[mt][nt], 0, 0, 0);
        }
    }

    #pragma unroll
    for (int mt = 0; mt < 3; ++mt) {
        int obase = w * 48 + mt * 16;
        if (obase < 32) {                         // theta: no pool
            #pragma unroll
            for (int nt = 0; nt < 8; ++nt)
                #pragma unroll
                for (int r = 0; r < 4; ++r) {
                    int o = obase + lg * 4 + r;
                    theta[((size_t)(n * 4096 + rp * 128 + nt * 16 + ll)) * 32 + o]
                        = f2bf(acc[mt][nt][r] + bcat[o]);
                }
        } else if (obase < 64) {                  // phi: pool -> (n,j,32)
            #pragma unroll
            for (int nt = 0; nt < 4; ++nt)
                #pragma unroll
                for (int r = 0; r < 4; ++r) {
                    int o = obase + lg * 4 + r;
                    float v = fmaxf(acc[mt][nt][r], acc[mt][nt + 4][r]);
                    float vv = fmaxf(v, __shfl_xor(v, 1));
                    if (!(ll & 1)) {
                        int q = nt * 8 + (ll >> 1);
                        phi_t[((size_t)(n * 1024 + rp * 32 + q)) * 32 + (o - 32)]
                            = f2bf(vv + bcat[o]);
                    }
                }
        } else {                                  // g: pool -> (n,c,1024)
            #pragma unroll
            for (int nt = 0; nt < 4; ++nt)
                #pragma unroll
                for (int r = 0; r < 4; ++r) {
                    int o = obase + lg * 4 + r;
                    float v = fmaxf(acc[mt][nt][r], acc[mt][nt + 4][r]);
                    float vv = fmaxf(v, __shfl_xor(v, 1));
                    if (!(ll & 1)) {
                        int q = nt * 8 + (ll >> 1);
                        g_t[((size_t)(n * 128 + (o - 64))) * 1024 + rp * 32 + q]
                            = f2bf(vv + bcat[o]);
                    }
                }
        }
    }
}

// ---------- fused attention: E=theta*phi^T (MFMA) -> exp -> P (LDS bf16, swizzled)
// ----------                  -> P*g^T (MFMA) -> normalize -> att_p (n,i,c) bf16
__global__ __launch_bounds__(128) void attn_k(const unsigned short* __restrict__ theta,
    const unsigned short* __restrict__ phi_t, const unsigned short* __restrict__ g_t,
    unsigned short* __restrict__ att_p)
{
    __shared__ __align__(16) unsigned short P[32 * 1024];   // 64 KB
    int n = blockIdx.x >> 7;
    int i0 = (blockIdx.x & 127) * 32;
    int t = threadIdx.x;
    int wv = t >> 6;
    int l = t & 63;
    int lg = l >> 4;
    int ll = l & 15;
    int riA = wv * 16 + ll;
    int rowD = wv * 16 + lg * 4;

    short8 afrag = *(const short8*)(theta + ((size_t)(n * 4096 + i0 + riA)) * 32 + lg * 8);

    const f32x4 zero = {0.f, 0.f, 0.f, 0.f};
    float rowsum[4] = {0.f, 0.f, 0.f, 0.f};
    #pragma unroll 2
    for (int jt = 0; jt < 64; ++jt) {
        int j0 = jt * 16;
        short8 bfrag = *(const short8*)(phi_t + ((size_t)(n * 1024 + j0 + ll)) * 32 + lg * 8);
        f32x4 e = __builtin_amdgcn_mfma_f32_16x16x32_bf16(afrag, bfrag, zero, 0, 0, 0);
        int col = j0 + ll;
        #pragma unroll
        for (int r = 0; r < 4; ++r) {
            float p = __expf(e[r]);              // |E| << 88, fp32-safe without max-sub
            rowsum[r] += p;
            int row = rowD + r;
            P[row * 1024 + (col ^ ((row & 7) << 3))] = f2bf(p);
        }
    }
    #pragma unroll
    for (int r = 0; r < 4; ++r) {
        #pragma unroll
        for (int off = 1; off < 16; off <<= 1)
            rowsum[r] += __shfl_xor(rowsum[r], off);
    }
    float inv[4];
    #pragma unroll
    for (int r = 0; r < 4; ++r) inv[r] = 1.f / rowsum[r];

    f32x4 acc[8];
    #pragma unroll
    for (int ct = 0; ct < 8; ++ct) acc[ct] = zero;

    #pragma unroll 2
    for (int kt = 0; kt < 32; ++kt) {
        int jb = kt * 32 + lg * 8;
        short8 pa = *(const short8*)&P[riA * 1024 + (jb ^ ((riA & 7) << 3))];
        const unsigned short* gb_base = g_t + ((size_t)(n * 128)) * 1024 + jb;
        #pragma unroll
        for (int ct = 0; ct < 8; ++ct) {
            short8 gb = *(const short8*)(gb_base + (size_t)(ct * 16 + ll) * 1024);
            acc[ct] = __builtin_amdgcn_mfma_f32_16x16x32_bf16(pa, gb, acc[ct], 0, 0, 0);
        }
    }
    __syncthreads();
    float* A = (float*)P;            // reuse as [128][33] fp32
    #pragma unroll
    for (int ct = 0; ct < 8; ++ct) {
        int c = ct * 16 + ll;
        #pragma unroll
        for (int r = 0; r < 4; ++r)
            A[c * 33 + rowD + r] = acc[ct][r] * inv[r];
    }
    __syncthreads();
    for (int ii = t; ii < 4096; ii += 128) {
        int c = ii & 127, il = ii >> 7;
        att_p[((size_t)(n * 4096 + i0 + il)) * 128 + c] = f2bf(A[c * 33 + il]);
    }
}

// ---------- final conv GEMM (M=256, K=128) + gamma*out + x ----------
__global__ __launch_bounds__(256) void out_mfma_k(const unsigned short* __restrict__ att_p,
    const unsigned short* __restrict__ owb, const float* __restrict__ ob,
    const float* __restrict__ x, const float* __restrict__ gamma, float* __restrict__ out)
{
    int rp = blockIdx.x;            // 0..31 (128-pixel groups)
    int n  = blockIdx.y;
    int t = threadIdx.x;
    int w = t >> 6;
    int l = t & 63;
    int lg = l >> 4, ll = l & 15;

    const unsigned short* abase = att_p + ((size_t)(n * 4096 + rp * 128)) * 128;
    const f32x4 zero = {0.f, 0.f, 0.f, 0.f};
    f32x4 acc[4][8];
    #pragma unroll
    for (int mt = 0; mt < 4; ++mt)
        #pragma unroll
        for (int nt = 0; nt < 8; ++nt) acc[mt][nt] = zero;

    for (int kk = 0; kk < 4; ++kk) {
        int ko = kk * 32 + lg * 8;
        short8 af[4];
        #pragma unroll
        for (int mt = 0; mt < 4; ++mt)
            af[mt] = *(const short8*)(owb + (size_t)(w * 64 + mt * 16 + ll) * 128 + ko);
        #pragma unroll
        for (int nt = 0; nt < 8; ++nt) {
            short8 bf = *(const short8*)(abase + (size_t)(nt * 16 + ll) * 128 + ko);
            #pragma unroll
            for (int mt = 0; mt < 4; ++mt)
                acc[mt][nt] = __builtin_amdgcn_mfma_f32_16x16x32_bf16(af[mt], bf, acc[mt][nt], 0, 0, 0);
        }
    }

    float gm = gamma[0];
    #pragma unroll
    for (int mt = 0; mt < 4; ++mt)
        #pragma unroll
        for (int nt = 0; nt < 8; ++nt)
            #pragma unroll
            for (int r = 0; r < 4; ++r) {
                int o = w * 64 + mt * 16 + lg * 4 + r;
                size_t oi = ((size_t)(n * 256 + o)) * 4096 + rp * 128 + nt * 16 + ll;
                out[oi] = fmaf(gm, acc[mt][nt][r] + ob[o], x[oi]);
            }
}

extern "C" void kernel_launch(void* const* d_in, const int* in_sizes, int n_in,
                              void* d_out, int out_size, void* d_ws, size_t ws_size,
                              hipStream_t stream) {
    const float* x       = (const float*)d_in[0];
    const float* theta_w = (const float*)d_in[1];
    const float* theta_b = (const float*)d_in[2];
    const float* phi_w   = (const float*)d_in[3];
    const float* phi_b   = (const float*)d_in[4];
    const float* g_w     = (const float*)d_in[5];
    const float* g_b     = (const float*)d_in[6];
    const float* out_w   = (const float*)d_in[7];
    const float* out_b   = (const float*)d_in[8];
    const float* gamma   = (const float*)d_in[9];
    float* out = (float*)d_out;

    char* w8 = (char*)d_ws;
    unsigned short* xb_t  = (unsigned short*)(w8);               // 16,777,216 B
    unsigned short* wb    = (unsigned short*)(w8 + 16777216);    //     98,304 B
    unsigned short* owb   = (unsigned short*)(w8 + 16875520);    //     65,536 B
    float*          bcat  = (float*)         (w8 + 16941056);    //      1,024 B
    unsigned short* theta = (unsigned short*)(w8 + 16942080);    //  2,097,152 B
    unsigned short* phi_t = (unsigned short*)(w8 + 19039232);    //    524,288 B
    unsigned short* g_t   = (unsigned short*)(w8 + 19563520);    //  2,097,152 B
    unsigned short* att_p = (unsigned short*)(w8 + 21660672);    //  8,388,608 B
                                                                 // end ~30.0 MB

    cvt_k<<<321, 256, 0, stream>>>(theta_w, theta_b, phi_w, phi_b, g_w, g_b, out_w,
                                   wb, owb, bcat);
    xt_k<<<dim3(64, 4, 8), 256, 0, stream>>>(x, xb_t);
    conv_qkv_k<<<dim3(32, 8), 256, 0, stream>>>(xb_t, wb, bcat, theta, phi_t, g_t);
    attn_k<<<1024, 128, 0, stream>>>(theta, phi_t, g_t, att_p);
    out_mfma_k<<<dim3(32, 8), 256, 0, stream>>>(att_p, owb, out_b, x, gamma, out);
}

// Round 4
// 215.146 us; speedup vs baseline: 17.5636x; 1.0715x over previous
//
#include <hip/hip_runtime.h>
#include <hip/hip_bf16.h>
#include <cstddef>

typedef __attribute__((ext_vector_type(8))) short short8;
typedef __attribute__((ext_vector_type(4))) float f32x4;

__device__ __forceinline__ unsigned short f2bf(float f) {
    union { float f; unsigned int u; } v; v.f = f;
    unsigned int r = v.u + 0x7fffu + ((v.u >> 16) & 1u);   // RNE
    return (unsigned short)(r >> 16);
}
__device__ __forceinline__ float bf2f(unsigned short u) {
    union { unsigned int u; float f; } v; v.u = ((unsigned int)u) << 16;
    return v.f;
}
__device__ __forceinline__ unsigned int pack2bf(float lo, float hi) {
    __hip_bfloat162 h2 = __float22bfloat162_rn(make_float2(lo, hi));
    union { __hip_bfloat162 h; unsigned int u; } v; v.h = h2;
    return v.u;
}

// ---------- x (n,c,pix) fp32 -> xb_t (n,pix,c) bf16, LDS tile transpose ----------
__global__ __launch_bounds__(256) void xt_k(const float* __restrict__ x,
                                            unsigned short* __restrict__ xb_t)
{
    __shared__ float T[64][65];
    int p0 = blockIdx.x * 64;
    int c0 = blockIdx.y * 64;
    int n  = blockIdx.z;
    int t = threadIdx.x;
    int r4 = t >> 6;
    int col = t & 63;
    const float* xp = x + ((size_t)(n * 256 + c0)) * 4096 + p0;
    #pragma unroll
    for (int it = 0; it < 16; ++it) {
        int c = it * 4 + r4;
        T[c][col] = xp[(size_t)c * 4096 + col];
    }
    __syncthreads();
    unsigned short* op = xb_t + ((size_t)(n * 4096 + p0)) * 256 + c0;
    #pragma unroll
    for (int it = 0; it < 16; ++it) {
        int p = it * 4 + r4;
        op[(size_t)p * 256 + col] = f2bf(T[col][p]);
    }
}

// ---------- weights/bias -> bf16 concat ----------
__global__ __launch_bounds__(256) void cvt_k(const float* __restrict__ tw,
    const float* __restrict__ tb, const float* __restrict__ pw, const float* __restrict__ pb,
    const float* __restrict__ gw, const float* __restrict__ gb, const float* __restrict__ ow,
    unsigned short* __restrict__ wb, unsigned short* __restrict__ owb, float* __restrict__ bcat)
{
    int idx = blockIdx.x * 256 + threadIdx.x;
    if (idx < 49152) {
        int o = idx >> 8, c = idx & 255;
        float v = (o < 32) ? tw[o * 256 + c] : (o < 64) ? pw[(o - 32) * 256 + c]
                                             : gw[(o - 64) * 256 + c];
        wb[idx] = f2bf(v);
    } else if (idx < 81920) {
        owb[idx - 49152] = f2bf(ow[idx - 49152]);
    } else if (idx < 82112) {
        int o = idx - 81920;
        bcat[o] = (o < 32) ? tb[o] : (o < 64) ? pb[o - 32] : gb[o - 64];
    }
}

// ---------- fused QKV conv GEMM + maxpool epilogue ----------
__global__ __launch_bounds__(256) void conv_qkv_k(const unsigned short* __restrict__ xb_t,
    const unsigned short* __restrict__ wb, const float* __restrict__ bcat,
    unsigned short* __restrict__ theta, unsigned short* __restrict__ phi_t,
    unsigned short* __restrict__ g_t)
{
    int rp = blockIdx.x;
    int n  = blockIdx.y;
    int t = threadIdx.x;
    int w = t >> 6;
    int l = t & 63;
    int lg = l >> 4, ll = l & 15;

    const unsigned short* xbase = xb_t + ((size_t)(n * 4096 + rp * 128)) * 256;
    const f32x4 zero = {0.f, 0.f, 0.f, 0.f};
    f32x4 acc[3][8];
    #pragma unroll
    for (int mt = 0; mt < 3; ++mt)
        #pragma unroll
        for (int nt = 0; nt < 8; ++nt) acc[mt][nt] = zero;

    #pragma unroll
    for (int kk = 0; kk < 8; ++kk) {
        int ko = kk * 32 + lg * 8;
        short8 af[3];
        #pragma unroll
        for (int mt = 0; mt < 3; ++mt)
            af[mt] = *(const short8*)(wb + (size_t)(w * 48 + mt * 16 + ll) * 256 + ko);
        #pragma unroll
        for (int nt = 0; nt < 8; ++nt) {
            short8 bf = *(const short8*)(xbase + (size_t)(nt * 16 + ll) * 256 + ko);
            #pragma unroll
            for (int mt = 0; mt < 3; ++mt)
                acc[mt][nt] = __builtin_amdgcn_mfma_f32_16x16x32_bf16(af[mt], bf, acc[mt][nt], 0, 0, 0);
        }
    }

    #pragma unroll
    for (int mt = 0; mt < 3; ++mt) {
        int obase = w * 48 + mt * 16;
        if (obase < 32) {
            #pragma unroll
            for (int nt = 0; nt < 8; ++nt)
                #pragma unroll
                for (int r = 0; r < 4; ++r) {
                    int o = obase + lg * 4 + r;
                    theta[((size_t)(n * 4096 + rp * 128 + nt * 16 + ll)) * 32 + o]
                        = f2bf(acc[mt][nt][r] + bcat[o]);
                }
        } else if (obase < 64) {
            #pragma unroll
            for (int nt = 0; nt < 4; ++nt)
                #pragma unroll
                for (int r = 0; r < 4; ++r) {
                    int o = obase + lg * 4 + r;
                    float v = fmaxf(acc[mt][nt][r], acc[mt][nt + 4][r]);
                    float vv = fmaxf(v, __shfl_xor(v, 1));
                    if (!(ll & 1)) {
                        int q = nt * 8 + (ll >> 1);
                        phi_t[((size_t)(n * 1024 + rp * 32 + q)) * 32 + (o - 32)]
                            = f2bf(vv + bcat[o]);
                    }
                }
        } else {
            #pragma unroll
            for (int nt = 0; nt < 4; ++nt)
                #pragma unroll
                for (int r = 0; r < 4; ++r) {
                    int o = obase + lg * 4 + r;
                    float v = fmaxf(acc[mt][nt][r], acc[mt][nt + 4][r]);
                    float vv = fmaxf(v, __shfl_xor(v, 1));
                    if (!(ll & 1)) {
                        int q = nt * 8 + (ll >> 1);
                        g_t[((size_t)(n * 128 + (o - 64))) * 1024 + rp * 32 + q]
                            = f2bf(vv + bcat[o]);
                    }
                }
        }
    }
}

// ---------- flash-style fused attention ----------
// Swapped QK^T (mfma(phi, theta)) -> lane-local P rows -> exp -> bf16 pack ->
// tiny per-wave LDS reshuffle -> PV MFMA accumulate -> normalize -> att_p (n,i,c).
__global__ __launch_bounds__(256, 4) void attn_k(const unsigned short* __restrict__ theta,
    const unsigned short* __restrict__ phi_t, const unsigned short* __restrict__ g_t,
    unsigned short* __restrict__ att_p)
{
    // per-wave, double-buffered P patch: 16 rows x 20 words (80B stride, 16B-aligned reads)
    __shared__ __align__(16) unsigned int Pl[4][2][16 * 20];   // 10 KB
    int n = blockIdx.x >> 6;
    int i0 = (blockIdx.x & 63) * 64;
    int t = threadIdx.x;
    int wv = t >> 6;
    int l = t & 63;
    int lg = l >> 4;
    int ll = l & 15;
    int i0w = i0 + wv * 16;

    // theta B-frag: B[k=d][col=i] <- theta[i0w+ll][lg*8+u]
    short8 bfrag = *(const short8*)(theta + ((size_t)(n * 4096 + i0w + ll)) * 32 + lg * 8);

    const unsigned short* phin  = phi_t + (size_t)n * 1024 * 32;
    const unsigned short* gbase = g_t + (size_t)n * 128 * 1024;

    const f32x4 zero = {0.f, 0.f, 0.f, 0.f};
    f32x4 acc[8];
    #pragma unroll
    for (int ct = 0; ct < 8; ++ct) acc[ct] = zero;
    float rs = 0.f;

    for (int jt = 0; jt < 32; ++jt) {
        int jb = jt * 32;
        // A-frags from phi (rows = j)
        short8 a0 = *(const short8*)(phin + (size_t)(jb + ll) * 32 + lg * 8);
        short8 a1 = *(const short8*)(phin + (size_t)(jb + 16 + ll) * 32 + lg * 8);
        f32x4 e0 = __builtin_amdgcn_mfma_f32_16x16x32_bf16(a0, bfrag, zero, 0, 0, 0);
        f32x4 e1 = __builtin_amdgcn_mfma_f32_16x16x32_bf16(a1, bfrag, zero, 0, 0, 0);
        // lane holds E^T[j = jb + 16t + 4*lg + r][i = i0w + ll]
        float p0[4], p1[4];
        #pragma unroll
        for (int r = 0; r < 4; ++r) {
            p0[r] = __expf(e0[r]);
            p1[r] = __expf(e1[r]);
            rs += p0[r] + p1[r];
        }
        unsigned int* Pb = &Pl[wv][jt & 1][0];
        int wbase = ll * 20;
        // word layout within row: m/2 = 8t + 2s + h  (s = writer's lg)
        Pb[wbase + 2 * lg + 0]     = pack2bf(p0[0], p0[1]);
        Pb[wbase + 2 * lg + 1]     = pack2bf(p0[2], p0[3]);
        Pb[wbase + 8 + 2 * lg + 0] = pack2bf(p1[0], p1[1]);
        Pb[wbase + 8 + 2 * lg + 1] = pack2bf(p1[2], p1[3]);
        // PV A-frag: P[i = i0w + ll][j = jb + lg*8 .. +8)
        short8 pa = *(const short8*)&Pb[ll * 20 + lg * 4];
        const unsigned short* gj = gbase + jb + lg * 8;
        #pragma unroll
        for (int ct = 0; ct < 8; ++ct) {
            short8 gb = *(const short8*)(gj + (size_t)(ct * 16 + ll) * 1024);
            acc[ct] = __builtin_amdgcn_mfma_f32_16x16x32_bf16(pa, gb, acc[ct], 0, 0, 0);
        }
    }

    // full rowsum for i = i0w + ll (partials live in the 4 lane-groups)
    rs += __shfl_xor(rs, 16);
    rs += __shfl_xor(rs, 32);
    float inv = 1.f / rs;
    // epilogue rows are i0w + lg*4 + r -> fetch matching inv
    float invr[4];
    #pragma unroll
    for (int r = 0; r < 4; ++r) invr[r] = __shfl(inv, lg * 4 + r);
    #pragma unroll
    for (int ct = 0; ct < 8; ++ct) {
        int c = ct * 16 + ll;
        #pragma unroll
        for (int r = 0; r < 4; ++r)
            att_p[((size_t)(n * 4096 + i0w + lg * 4 + r)) * 128 + c]
                = f2bf(acc[ct][r] * invr[r]);
    }
}

// ---------- final conv GEMM (M=256, K=128, N=64/block) + gamma*out + x ----------
__global__ __launch_bounds__(256) void out_mfma_k(const unsigned short* __restrict__ att_p,
    const unsigned short* __restrict__ owb, const float* __restrict__ ob,
    const float* __restrict__ x, const float* __restrict__ gamma, float* __restrict__ out)
{
    int px0 = blockIdx.x * 64;
    int n  = blockIdx.y;
    int t = threadIdx.x;
    int w = t >> 6;
    int l = t & 63;
    int lg = l >> 4, ll = l & 15;

    const unsigned short* abase = att_p + ((size_t)(n * 4096 + px0)) * 128;
    const f32x4 zero = {0.f, 0.f, 0.f, 0.f};
    f32x4 acc[4][4];
    #pragma unroll
    for (int mt = 0; mt < 4; ++mt)
        #pragma unroll
        for (int nt = 0; nt < 4; ++nt) acc[mt][nt] = zero;

    #pragma unroll
    for (int kk = 0; kk < 4; ++kk) {
        int ko = kk * 32 + lg * 8;
        short8 af[4];
        #pragma unroll
        for (int mt = 0; mt < 4; ++mt)
            af[mt] = *(const short8*)(owb + (size_t)(w * 64 + mt * 16 + ll) * 128 + ko);
        #pragma unroll
        for (int nt = 0; nt < 4; ++nt) {
            short8 bf = *(const short8*)(abase + (size_t)(nt * 16 + ll) * 128 + ko);
            #pragma unroll
            for (int mt = 0; mt < 4; ++mt)
                acc[mt][nt] = __builtin_amdgcn_mfma_f32_16x16x32_bf16(af[mt], bf, acc[mt][nt], 0, 0, 0);
        }
    }

    float gm = gamma[0];
    #pragma unroll
    for (int mt = 0; mt < 4; ++mt)
        #pragma unroll
        for (int nt = 0; nt < 4; ++nt)
            #pragma unroll
            for (int r = 0; r < 4; ++r) {
                int o = w * 64 + mt * 16 + lg * 4 + r;
                size_t oi = ((size_t)(n * 256 + o)) * 4096 + px0 + nt * 16 + ll;
                out[oi] = fmaf(gm, acc[mt][nt][r] + ob[o], x[oi]);
            }
}

extern "C" void kernel_launch(void* const* d_in, const int* in_sizes, int n_in,
                              void* d_out, int out_size, void* d_ws, size_t ws_size,
                              hipStream_t stream) {
    const float* x       = (const float*)d_in[0];
    const float* theta_w = (const float*)d_in[1];
    const float* theta_b = (const float*)d_in[2];
    const float* phi_w   = (const float*)d_in[3];
    const float* phi_b   = (const float*)d_in[4];
    const float* g_w     = (const float*)d_in[5];
    const float* g_b     = (const float*)d_in[6];
    const float* out_w   = (const float*)d_in[7];
    const float* out_b   = (const float*)d_in[8];
    const float* gamma   = (const float*)d_in[9];
    float* out = (float*)d_out;

    char* w8 = (char*)d_ws;
    unsigned short* xb_t  = (unsigned short*)(w8);               // 16,777,216 B
    unsigned short* wb    = (unsigned short*)(w8 + 16777216);
    unsigned short* owb   = (unsigned short*)(w8 + 16875520);
    float*          bcat  = (float*)         (w8 + 16941056);
    unsigned short* theta = (unsigned short*)(w8 + 16942080);
    unsigned short* phi_t = (unsigned short*)(w8 + 19039232);
    unsigned short* g_t   = (unsigned short*)(w8 + 19563520);
    unsigned short* att_p = (unsigned short*)(w8 + 21660672);

    cvt_k<<<321, 256, 0, stream>>>(theta_w, theta_b, phi_w, phi_b, g_w, g_b, out_w,
                                   wb, owb, bcat);
    xt_k<<<dim3(64, 4, 8), 256, 0, stream>>>(x, xb_t);
    conv_qkv_k<<<dim3(32, 8), 256, 0, stream>>>(xb_t, wb, bcat, theta, phi_t, g_t);
    attn_k<<<512, 256, 0, stream>>>(theta, phi_t, g_t, att_p);
    out_mfma_k<<<dim3(64, 8), 256, 0, stream>>>(att_p, owb, out_b, x, gamma, out);
}

// Round 5
// 199.531 us; speedup vs baseline: 18.9381x; 1.0783x over previous
//
#include <hip/hip_runtime.h>
#include <hip/hip_bf16.h>
#include <cstddef>

typedef __attribute__((ext_vector_type(8))) short short8;
typedef __attribute__((ext_vector_type(4))) float f32x4;
typedef __attribute__((ext_vector_type(4))) unsigned int u32x4;
typedef __attribute__((ext_vector_type(2))) unsigned int u32x2;

__device__ __forceinline__ unsigned short f2bf(float f) {
    union { float f; unsigned int u; } v; v.f = f;
    unsigned int r = v.u + 0x7fffu + ((v.u >> 16) & 1u);   // RNE
    return (unsigned short)(r >> 16);
}
__device__ __forceinline__ unsigned int pack2bf(float lo, float hi) {
    __hip_bfloat162 h2 = __float22bfloat162_rn(make_float2(lo, hi));
    union { __hip_bfloat162 h; unsigned int u; } v; v.h = h2;
    return v.u;
}

// ---------- weights/bias -> bf16 concat ----------
__global__ __launch_bounds__(256) void cvt_k(const float* __restrict__ tw,
    const float* __restrict__ tb, const float* __restrict__ pw, const float* __restrict__ pb,
    const float* __restrict__ gw, const float* __restrict__ gb, const float* __restrict__ ow,
    unsigned short* __restrict__ wb, unsigned short* __restrict__ owb, float* __restrict__ bcat)
{
    int idx = blockIdx.x * 256 + threadIdx.x;
    if (idx < 49152) {
        int o = idx >> 8, c = idx & 255;
        float v = (o < 32) ? tw[o * 256 + c] : (o < 64) ? pw[(o - 32) * 256 + c]
                                             : gw[(o - 64) * 256 + c];
        wb[idx] = f2bf(v);
    } else if (idx < 81920) {
        owb[idx - 49152] = f2bf(ow[idx - 49152]);
    } else if (idx < 82112) {
        int o = idx - 81920;
        bcat[o] = (o < 32) ? tb[o] : (o < 64) ? pb[o - 32] : gb[o - 64];
    }
}

// ---------- fused QKV conv GEMM: x staged fp32->bf16 via LDS (dbuf), + maxpool epi ----
// block: 64 pixels (rows {2rp,2rp+1} x cols cb*32..+32), M=192 outputs, K=256.
__global__ __launch_bounds__(256) void conv_qkv_k(const float* __restrict__ x,
    const unsigned short* __restrict__ wb, const float* __restrict__ bcat,
    unsigned short* __restrict__ theta, unsigned short* __restrict__ phi_t,
    unsigned short* __restrict__ g_t)
{
    __shared__ __align__(16) unsigned int xT[2][64 * 24];   // 64 rows x 24 words, dbuf
    int bx = blockIdx.x;
    int n  = blockIdx.y;
    int rp = bx >> 1, cb = bx & 1;
    int t = threadIdx.x;
    int w = t >> 6;
    int l = t & 63;
    int lg = l >> 4, ll = l & 15;

    // staging ids
    int q = t & 63, oct = t >> 6;
    int gpix_s = (2 * rp + (q >> 5)) * 64 + cb * 32 + (q & 31);
    const float* xp = x + (size_t)n * 256 * 4096 + gpix_s;

    const f32x4 zero = {0.f, 0.f, 0.f, 0.f};
    f32x4 acc[3][4];
    #pragma unroll
    for (int mt = 0; mt < 3; ++mt)
        #pragma unroll
        for (int nt = 0; nt < 4; ++nt) acc[mt][nt] = zero;

    // prologue: stage chunk 0
    {
        float xv[8];
        #pragma unroll
        for (int u = 0; u < 8; ++u) xv[u] = xp[(size_t)(oct * 8 + u) * 4096];
        u32x4 pk = {pack2bf(xv[0], xv[1]), pack2bf(xv[2], xv[3]),
                    pack2bf(xv[4], xv[5]), pack2bf(xv[6], xv[7])};
        *(u32x4*)&xT[0][q * 24 + oct * 4] = pk;
    }
    for (int kk = 0; kk < 8; ++kk) {
        __syncthreads();
        float nv[8];
        if (kk < 7) {
            #pragma unroll
            for (int u = 0; u < 8; ++u)
                nv[u] = xp[(size_t)((kk + 1) * 32 + oct * 8 + u) * 4096];
        }
        int ko = kk * 32 + lg * 8;
        short8 af[3];
        #pragma unroll
        for (int mt = 0; mt < 3; ++mt)
            af[mt] = *(const short8*)(wb + (size_t)(w * 48 + mt * 16 + ll) * 256 + ko);
        #pragma unroll
        for (int nt = 0; nt < 4; ++nt) {
            short8 bf = *(const short8*)&xT[kk & 1][(nt * 16 + ll) * 24 + lg * 4];
            #pragma unroll
            for (int mt = 0; mt < 3; ++mt)
                acc[mt][nt] = __builtin_amdgcn_mfma_f32_16x16x32_bf16(af[mt], bf, acc[mt][nt], 0, 0, 0);
        }
        if (kk < 7) {
            u32x4 pk = {pack2bf(nv[0], nv[1]), pack2bf(nv[2], nv[3]),
                        pack2bf(nv[4], nv[5]), pack2bf(nv[6], nv[7])};
            *(u32x4*)&xT[(kk + 1) & 1][q * 24 + oct * 4] = pk;
        }
    }

    #pragma unroll
    for (int mt = 0; mt < 3; ++mt) {
        int obase = w * 48 + mt * 16;
        if (obase < 32) {                         // theta: no pool
            #pragma unroll
            for (int nt = 0; nt < 4; ++nt) {
                int qq = nt * 16 + ll;
                int gpix = (2 * rp + (qq >> 5)) * 64 + cb * 32 + (qq & 31);
                #pragma unroll
                for (int r = 0; r < 4; ++r) {
                    int o = obase + lg * 4 + r;
                    theta[((size_t)(n * 4096 + gpix)) * 32 + o]
                        = f2bf(acc[mt][nt][r] + bcat[o]);
                }
            }
        } else if (obase < 64) {                  // phi: pool -> (n,j,32)
            #pragma unroll
            for (int nt = 0; nt < 2; ++nt)
                #pragma unroll
                for (int r = 0; r < 4; ++r) {
                    int o = obase + lg * 4 + r;
                    float v = fmaxf(acc[mt][nt][r], acc[mt][nt + 2][r]);
                    float vv = fmaxf(v, __shfl_xor(v, 1));
                    if (!(ll & 1)) {
                        int j = rp * 32 + cb * 16 + nt * 8 + (ll >> 1);
                        phi_t[((size_t)(n * 1024 + j)) * 32 + (o - 32)]
                            = f2bf(vv + bcat[o]);
                    }
                }
        } else {                                  // g: pool -> (n,c,1024)
            #pragma unroll
            for (int nt = 0; nt < 2; ++nt)
                #pragma unroll
                for (int r = 0; r < 4; ++r) {
                    int o = obase + lg * 4 + r;
                    float v = fmaxf(acc[mt][nt][r], acc[mt][nt + 2][r]);
                    float vv = fmaxf(v, __shfl_xor(v, 1));
                    if (!(ll & 1)) {
                        int j = rp * 32 + cb * 16 + nt * 8 + (ll >> 1);
                        g_t[((size_t)(n * 128 + (o - 64))) * 1024 + j]
                            = f2bf(vv + bcat[o]);
                    }
                }
        }
    }
}

// ---------- flash-style fused attention, software-pipelined (PV lags one j-tile) ----
__global__ __launch_bounds__(256, 2) void attn_k(const unsigned short* __restrict__ theta,
    const unsigned short* __restrict__ phi_t, const unsigned short* __restrict__ g_t,
    unsigned short* __restrict__ att_p)
{
    // per-wave dbuf P patch: 16 rows x 24 words (96B stride; b128 write, 2x b64 read)
    __shared__ __align__(16) unsigned int Pl[4][2][16 * 24];   // 12 KB
    int n = blockIdx.x >> 6;
    int i0 = (blockIdx.x & 63) * 64;
    int t = threadIdx.x;
    int wv = t >> 6;
    int l = t & 63;
    int lg = l >> 4;
    int ll = l & 15;
    int i0w = i0 + wv * 16;

    short8 bfrag = *(const short8*)(theta + ((size_t)(n * 4096 + i0w + ll)) * 32 + lg * 8);

    const unsigned short* phin  = phi_t + (size_t)n * 1024 * 32;
    const unsigned short* gbase = g_t + (size_t)n * 128 * 1024;

    unsigned int* Pw[2] = { &Pl[wv][0][0], &Pl[wv][1][0] };
    int wrw = ll * 24 + lg * 4;                              // write word
    int ra  = ll * 24 + ((lg & 1) << 3) + ((lg >> 1) << 1);  // read word base

    const f32x4 zero = {0.f, 0.f, 0.f, 0.f};
    f32x4 acc[8];
    #pragma unroll
    for (int ct = 0; ct < 8; ++ct) acc[ct] = zero;
    float rs = 0.f;
    short8 pa;

    // ---- stage jt = 0 ----
    {
        short8 a0 = *(const short8*)(phin + (size_t)(ll) * 32 + lg * 8);
        short8 a1 = *(const short8*)(phin + (size_t)(16 + ll) * 32 + lg * 8);
        f32x4 e0 = __builtin_amdgcn_mfma_f32_16x16x32_bf16(a0, bfrag, zero, 0, 0, 0);
        f32x4 e1 = __builtin_amdgcn_mfma_f32_16x16x32_bf16(a1, bfrag, zero, 0, 0, 0);
        float p0[4], p1[4];
        #pragma unroll
        for (int r = 0; r < 4; ++r) {
            p0[r] = __expf(e0[r]); p1[r] = __expf(e1[r]);
            rs += p0[r] + p1[r];
        }
        u32x4 qk = {pack2bf(p0[0], p0[1]), pack2bf(p0[2], p0[3]),
                    pack2bf(p1[0], p1[1]), pack2bf(p1[2], p1[3])};
        *(u32x4*)&Pw[0][wrw] = qk;
        u32x2 w01 = *(u32x2*)&Pw[0][ra];
        u32x2 w23 = *(u32x2*)&Pw[0][ra + 4];
        union { u32x4 u; short8 s; } cv;
        cv.u = (u32x4){w01[0], w01[1], w23[0], w23[1]};
        pa = cv.s;
    }
    for (int jt = 1; jt < 32; ++jt) {
        int jb = jt * 32;
        short8 a0 = *(const short8*)(phin + (size_t)(jb + ll) * 32 + lg * 8);
        short8 a1 = *(const short8*)(phin + (size_t)(jb + 16 + ll) * 32 + lg * 8);
        f32x4 e0 = __builtin_amdgcn_mfma_f32_16x16x32_bf16(a0, bfrag, zero, 0, 0, 0);
        f32x4 e1 = __builtin_amdgcn_mfma_f32_16x16x32_bf16(a1, bfrag, zero, 0, 0, 0);
        float p0[4], p1[4];
        #pragma unroll
        for (int r = 0; r < 4; ++r) {
            p0[r] = __expf(e0[r]); p1[r] = __expf(e1[r]);
            rs += p0[r] + p1[r];
        }
        unsigned int* Pb = Pw[jt & 1];
        u32x4 qk = {pack2bf(p0[0], p0[1]), pack2bf(p0[2], p0[3]),
                    pack2bf(p1[0], p1[1]), pack2bf(p1[2], p1[3])};
        *(u32x4*)&Pb[wrw] = qk;
        // PV for jt-1 (independent of this tile's chain -> overlaps)
        const unsigned short* gj = gbase + (jt - 1) * 32 + lg * 8;
        #pragma unroll
        for (int ct = 0; ct < 8; ++ct) {
            short8 gb = *(const short8*)(gj + (size_t)(ct * 16 + ll) * 1024);
            acc[ct] = __builtin_amdgcn_mfma_f32_16x16x32_bf16(pa, gb, acc[ct], 0, 0, 0);
        }
        u32x2 w01 = *(u32x2*)&Pb[ra];
        u32x2 w23 = *(u32x2*)&Pb[ra + 4];
        union { u32x4 u; short8 s; } cv;
        cv.u = (u32x4){w01[0], w01[1], w23[0], w23[1]};
        pa = cv.s;
    }
    {   // final PV (jt = 31)
        const unsigned short* gj = gbase + 31 * 32 + lg * 8;
        #pragma unroll
        for (int ct = 0; ct < 8; ++ct) {
            short8 gb = *(const short8*)(gj + (size_t)(ct * 16 + ll) * 1024);
            acc[ct] = __builtin_amdgcn_mfma_f32_16x16x32_bf16(pa, gb, acc[ct], 0, 0, 0);
        }
    }

    rs += __shfl_xor(rs, 16);
    rs += __shfl_xor(rs, 32);
    float inv = 1.f / rs;
    float invr[4];
    #pragma unroll
    for (int r = 0; r < 4; ++r) invr[r] = __shfl(inv, lg * 4 + r);
    #pragma unroll
    for (int ct = 0; ct < 8; ++ct) {
        int c = ct * 16 + ll;
        #pragma unroll
        for (int r = 0; r < 4; ++r)
            att_p[((size_t)(n * 4096 + i0w + lg * 4 + r)) * 128 + c]
                = f2bf(acc[ct][r] * invr[r]);
    }
}

// ---------- final conv GEMM (M=256, K=128, N=32/block) + gamma*out + x ----------
__global__ __launch_bounds__(256) void out_mfma_k(const unsigned short* __restrict__ att_p,
    const unsigned short* __restrict__ owb, const float* __restrict__ ob,
    const float* __restrict__ x, const float* __restrict__ gamma, float* __restrict__ out)
{
    int px0 = blockIdx.x * 32;
    int n  = blockIdx.y;
    int t = threadIdx.x;
    int w = t >> 6;
    int l = t & 63;
    int lg = l >> 4, ll = l & 15;

    const unsigned short* abase = att_p + ((size_t)(n * 4096 + px0)) * 128;
    const f32x4 zero = {0.f, 0.f, 0.f, 0.f};
    f32x4 acc[4][2];
    #pragma unroll
    for (int mt = 0; mt < 4; ++mt)
        #pragma unroll
        for (int nt = 0; nt < 2; ++nt) acc[mt][nt] = zero;

    #pragma unroll
    for (int kk = 0; kk < 4; ++kk) {
        int ko = kk * 32 + lg * 8;
        short8 af[4];
        #pragma unroll
        for (int mt = 0; mt < 4; ++mt)
            af[mt] = *(const short8*)(owb + (size_t)(w * 64 + mt * 16 + ll) * 128 + ko);
        #pragma unroll
        for (int nt = 0; nt < 2; ++nt) {
            short8 bf = *(const short8*)(abase + (size_t)(nt * 16 + ll) * 128 + ko);
            #pragma unroll
            for (int mt = 0; mt < 4; ++mt)
                acc[mt][nt] = __builtin_amdgcn_mfma_f32_16x16x32_bf16(af[mt], bf, acc[mt][nt], 0, 0, 0);
        }
    }

    float gm = gamma[0];
    #pragma unroll
    for (int mt = 0; mt < 4; ++mt)
        #pragma unroll
        for (int nt = 0; nt < 2; ++nt)
            #pragma unroll
            for (int r = 0; r < 4; ++r) {
                int o = w * 64 + mt * 16 + lg * 4 + r;
                size_t oi = ((size_t)(n * 256 + o)) * 4096 + px0 + nt * 16 + ll;
                out[oi] = fmaf(gm, acc[mt][nt][r] + ob[o], x[oi]);
            }
}

extern "C" void kernel_launch(void* const* d_in, const int* in_sizes, int n_in,
                              void* d_out, int out_size, void* d_ws, size_t ws_size,
                              hipStream_t stream) {
    const float* x       = (const float*)d_in[0];
    const float* theta_w = (const float*)d_in[1];
    const float* theta_b = (const float*)d_in[2];
    const float* phi_w   = (const float*)d_in[3];
    const float* phi_b   = (const float*)d_in[4];
    const float* g_w     = (const float*)d_in[5];
    const float* g_b     = (const float*)d_in[6];
    const float* out_w   = (const float*)d_in[7];
    const float* out_b   = (const float*)d_in[8];
    const float* gamma   = (const float*)d_in[9];
    float* out = (float*)d_out;

    char* w8 = (char*)d_ws;
    unsigned short* wb    = (unsigned short*)(w8);               //    98,304 B
    unsigned short* owb   = (unsigned short*)(w8 + 98304);       //    65,536 B
    float*          bcat  = (float*)         (w8 + 163840);      //     1,024 B
    unsigned short* theta = (unsigned short*)(w8 + 164864);      // 2,097,152 B
    unsigned short* phi_t = (unsigned short*)(w8 + 2262016);     //   524,288 B
    unsigned short* g_t   = (unsigned short*)(w8 + 2786304);     // 2,097,152 B
    unsigned short* att_p = (unsigned short*)(w8 + 4883456);     // 8,388,608 B
                                                                 // end ~13.3 MB

    cvt_k<<<321, 256, 0, stream>>>(theta_w, theta_b, phi_w, phi_b, g_w, g_b, out_w,
                                   wb, owb, bcat);
    conv_qkv_k<<<dim3(64, 8), 256, 0, stream>>>(x, wb, bcat, theta, phi_t, g_t);
    attn_k<<<512, 256, 0, stream>>>(theta, phi_t, g_t, att_p);
    out_mfma_k<<<dim3(128, 8), 256, 0, stream>>>(att_p, owb, out_b, x, gamma, out);
}

// Round 6
// 196.283 us; speedup vs baseline: 19.2515x; 1.0165x over previous
//
#include <hip/hip_runtime.h>
#include <hip/hip_bf16.h>
#include <cstddef>

typedef __attribute__((ext_vector_type(8))) short short8;
typedef __attribute__((ext_vector_type(4))) float f32x4;
typedef __attribute__((ext_vector_type(4))) unsigned int u32x4;

__device__ __forceinline__ unsigned short f2bf(float f) {
    union { float f; unsigned int u; } v; v.f = f;
    unsigned int r = v.u + 0x7fffu + ((v.u >> 16) & 1u);   // RNE
    return (unsigned short)(r >> 16);
}
__device__ __forceinline__ unsigned int pack2bf(float lo, float hi) {
    __hip_bfloat162 h2 = __float22bfloat162_rn(make_float2(lo, hi));
    union { __hip_bfloat162 h; unsigned int u; } v; v.h = h2;
    return v.u;
}

// ---------- weights/bias -> bf16 concat ----------
__global__ __launch_bounds__(256) void cvt_k(const float* __restrict__ tw,
    const float* __restrict__ tb, const float* __restrict__ pw, const float* __restrict__ pb,
    const float* __restrict__ gw, const float* __restrict__ gb, const float* __restrict__ ow,
    unsigned short* __restrict__ wb, unsigned short* __restrict__ owb, float* __restrict__ bcat)
{
    int idx = blockIdx.x * 256 + threadIdx.x;
    if (idx < 49152) {
        int o = idx >> 8, c = idx & 255;
        float v = (o < 32) ? tw[o * 256 + c] : (o < 64) ? pw[(o - 32) * 256 + c]
                                             : gw[(o - 64) * 256 + c];
        wb[idx] = f2bf(v);
    } else if (idx < 81920) {
        owb[idx - 49152] = f2bf(ow[idx - 49152]);
    } else if (idx < 82112) {
        int o = idx - 81920;
        bcat[o] = (o < 32) ? tb[o] : (o < 64) ? pb[o - 32] : gb[o - 64];
    }
}

// ---------- fused QKV conv GEMM: x staged fp32->bf16 via LDS (dbuf), + maxpool epi ----
__global__ __launch_bounds__(256) void conv_qkv_k(const float* __restrict__ x,
    const unsigned short* __restrict__ wb, const float* __restrict__ bcat,
    unsigned short* __restrict__ theta, unsigned short* __restrict__ phi_t,
    unsigned short* __restrict__ g_t)
{
    __shared__ __align__(16) unsigned int xT[2][64 * 24];
    int bx = blockIdx.x;
    int n  = blockIdx.y;
    int rp = bx >> 1, cb = bx & 1;
    int t = threadIdx.x;
    int w = t >> 6;
    int l = t & 63;
    int lg = l >> 4, ll = l & 15;

    int q = t & 63, oct = t >> 6;
    int gpix_s = (2 * rp + (q >> 5)) * 64 + cb * 32 + (q & 31);
    const float* xp = x + (size_t)n * 256 * 4096 + gpix_s;

    const f32x4 zero = {0.f, 0.f, 0.f, 0.f};
    f32x4 acc[3][4];
    #pragma unroll
    for (int mt = 0; mt < 3; ++mt)
        #pragma unroll
        for (int nt = 0; nt < 4; ++nt) acc[mt][nt] = zero;

    {
        float xv[8];
        #pragma unroll
        for (int u = 0; u < 8; ++u) xv[u] = xp[(size_t)(oct * 8 + u) * 4096];
        u32x4 pk = {pack2bf(xv[0], xv[1]), pack2bf(xv[2], xv[3]),
                    pack2bf(xv[4], xv[5]), pack2bf(xv[6], xv[7])};
        *(u32x4*)&xT[0][q * 24 + oct * 4] = pk;
    }
    for (int kk = 0; kk < 8; ++kk) {
        __syncthreads();
        float nv[8];
        if (kk < 7) {
            #pragma unroll
            for (int u = 0; u < 8; ++u)
                nv[u] = xp[(size_t)((kk + 1) * 32 + oct * 8 + u) * 4096];
        }
        int ko = kk * 32 + lg * 8;
        short8 af[3];
        #pragma unroll
        for (int mt = 0; mt < 3; ++mt)
            af[mt] = *(const short8*)(wb + (size_t)(w * 48 + mt * 16 + ll) * 256 + ko);
        #pragma unroll
        for (int nt = 0; nt < 4; ++nt) {
            short8 bf = *(const short8*)&xT[kk & 1][(nt * 16 + ll) * 24 + lg * 4];
            #pragma unroll
            for (int mt = 0; mt < 3; ++mt)
                acc[mt][nt] = __builtin_amdgcn_mfma_f32_16x16x32_bf16(af[mt], bf, acc[mt][nt], 0, 0, 0);
        }
        if (kk < 7) {
            u32x4 pk = {pack2bf(nv[0], nv[1]), pack2bf(nv[2], nv[3]),
                        pack2bf(nv[4], nv[5]), pack2bf(nv[6], nv[7])};
            *(u32x4*)&xT[(kk + 1) & 1][q * 24 + oct * 4] = pk;
        }
    }

    #pragma unroll
    for (int mt = 0; mt < 3; ++mt) {
        int obase = w * 48 + mt * 16;
        if (obase < 32) {
            #pragma unroll
            for (int nt = 0; nt < 4; ++nt) {
                int qq = nt * 16 + ll;
                int gpix = (2 * rp + (qq >> 5)) * 64 + cb * 32 + (qq & 31);
                #pragma unroll
                for (int r = 0; r < 4; ++r) {
                    int o = obase + lg * 4 + r;
                    theta[((size_t)(n * 4096 + gpix)) * 32 + o]
                        = f2bf(acc[mt][nt][r] + bcat[o]);
                }
            }
        } else if (obase < 64) {
            #pragma unroll
            for (int nt = 0; nt < 2; ++nt)
                #pragma unroll
                for (int r = 0; r < 4; ++r) {
                    int o = obase + lg * 4 + r;
                    float v = fmaxf(acc[mt][nt][r], acc[mt][nt + 2][r]);
                    float vv = fmaxf(v, __shfl_xor(v, 1));
                    if (!(ll & 1)) {
                        int j = rp * 32 + cb * 16 + nt * 8 + (ll >> 1);
                        phi_t[((size_t)(n * 1024 + j)) * 32 + (o - 32)]
                            = f2bf(vv + bcat[o]);
                    }
                }
        } else {
            #pragma unroll
            for (int nt = 0; nt < 2; ++nt)
                #pragma unroll
                for (int r = 0; r < 4; ++r) {
                    int o = obase + lg * 4 + r;
                    float v = fmaxf(acc[mt][nt][r], acc[mt][nt + 2][r]);
                    float vv = fmaxf(v, __shfl_xor(v, 1));
                    if (!(ll & 1)) {
                        int j = rp * 32 + cb * 16 + nt * 8 + (ll >> 1);
                        g_t[((size_t)(n * 128 + (o - 64))) * 1024 + j]
                            = f2bf(vv + bcat[o]);
                    }
                }
        }
    }
}

// ---------- flash attention, zero-LDS main loop ----------
// Permuted-phi QK^T makes each lane's E output exactly its PV A-fragment:
//   a0 row = jb + 8*(ll>>2) + (ll&3), a1 = +4  =>  lane(lg,ll) holds
//   E[jb+8lg+u][i0w+ll], u=0..7  ==  P-Afrag[m=ll][k=8lg+u].
// Wave = 16 i x 512 j; block = 2 i-groups x 2 j-halves; partial O/rowsum
// combined via small LDS at the end.
__global__ __launch_bounds__(256, 4) void attn_k(const unsigned short* __restrict__ theta,
    const unsigned short* __restrict__ phi_t, const unsigned short* __restrict__ g_t,
    unsigned short* __restrict__ att_p)
{
    __shared__ float comb[2][64][34];   // [h][lane][0..31 acc, 32 rs] = 17408 B
    int b = blockIdx.x;
    int swz = (b & 7) * 128 + (b >> 3);      // XCD-contiguous (1024 % 8 == 0)
    int n = swz >> 7;
    int i0 = (swz & 127) * 32;
    int t = threadIdx.x;
    int wv = t >> 6;
    int h = wv >> 1, v = wv & 1;
    int l = t & 63;
    int lg = l >> 4, ll = l & 15;
    int i0w = i0 + h * 16;

    short8 bfrag = *(const short8*)(theta + ((size_t)(n * 4096 + i0w + ll)) * 32 + lg * 8);
    const unsigned short* phin  = phi_t + (size_t)n * 1024 * 32;
    const unsigned short* gbase = g_t + (size_t)n * 128 * 1024;
    int prow = 8 * (ll >> 2) + (ll & 3);

    const f32x4 zero = {0.f, 0.f, 0.f, 0.f};
    f32x4 acc[8];
    #pragma unroll
    for (int ct = 0; ct < 8; ++ct) acc[ct] = zero;
    float rs = 0.f;

    #pragma unroll 2
    for (int jt = 0; jt < 16; ++jt) {
        int jb = v * 512 + jt * 32;
        short8 a0 = *(const short8*)(phin + (size_t)(jb + prow) * 32 + lg * 8);
        short8 a1 = *(const short8*)(phin + (size_t)(jb + prow + 4) * 32 + lg * 8);
        f32x4 e0 = __builtin_amdgcn_mfma_f32_16x16x32_bf16(a0, bfrag, zero, 0, 0, 0);
        f32x4 e1 = __builtin_amdgcn_mfma_f32_16x16x32_bf16(a1, bfrag, zero, 0, 0, 0);
        float p0[4], p1[4];
        #pragma unroll
        for (int r = 0; r < 4; ++r) {
            p0[r] = __expf(e0[r]); p1[r] = __expf(e1[r]);
            rs += p0[r] + p1[r];
        }
        union { u32x4 u; short8 s; } cv;
        cv.u = (u32x4){pack2bf(p0[0], p0[1]), pack2bf(p0[2], p0[3]),
                       pack2bf(p1[0], p1[1]), pack2bf(p1[2], p1[3])};
        short8 pa = cv.s;
        const unsigned short* gj = gbase + jb + lg * 8;
        #pragma unroll
        for (int ct = 0; ct < 8; ++ct) {
            short8 gb = *(const short8*)(gj + (size_t)(ct * 16 + ll) * 1024);
            acc[ct] = __builtin_amdgcn_mfma_f32_16x16x32_bf16(pa, gb, acc[ct], 0, 0, 0);
        }
    }

    rs += __shfl_xor(rs, 16);
    rs += __shfl_xor(rs, 32);

    if (v == 1) {
        #pragma unroll
        for (int ct = 0; ct < 8; ++ct)
            #pragma unroll
            for (int r = 0; r < 4; ++r)
                comb[h][l][ct * 4 + r] = acc[ct][r];
        if (lg == 0) comb[h][ll][32] = rs;
    }
    __syncthreads();
    if (v == 0) {
        float inv = 1.f / (rs + comb[h][ll][32]);
        float invr[4];
        #pragma unroll
        for (int r = 0; r < 4; ++r) invr[r] = __shfl(inv, lg * 4 + r);
        #pragma unroll
        for (int ct = 0; ct < 8; ++ct) {
            int c = ct * 16 + ll;
            #pragma unroll
            for (int r = 0; r < 4; ++r) {
                float val = acc[ct][r] + comb[h][l][ct * 4 + r];
                att_p[((size_t)(n * 4096 + i0w + lg * 4 + r)) * 128 + c]
                    = f2bf(val * invr[r]);
            }
        }
    }
}

// ---------- final conv GEMM (M=256, K=128, N=32/block) + gamma*out + x ----------
__global__ __launch_bounds__(256) void out_mfma_k(const unsigned short* __restrict__ att_p,
    const unsigned short* __restrict__ owb, const float* __restrict__ ob,
    const float* __restrict__ x, const float* __restrict__ gamma, float* __restrict__ out)
{
    int px0 = blockIdx.x * 32;
    int n  = blockIdx.y;
    int t = threadIdx.x;
    int w = t >> 6;
    int l = t & 63;
    int lg = l >> 4, ll = l & 15;

    const unsigned short* abase = att_p + ((size_t)(n * 4096 + px0)) * 128;
    const f32x4 zero = {0.f, 0.f, 0.f, 0.f};
    f32x4 acc[4][2];
    #pragma unroll
    for (int mt = 0; mt < 4; ++mt)
        #pragma unroll
        for (int nt = 0; nt < 2; ++nt) acc[mt][nt] = zero;

    #pragma unroll
    for (int kk = 0; kk < 4; ++kk) {
        int ko = kk * 32 + lg * 8;
        short8 af[4];
        #pragma unroll
        for (int mt = 0; mt < 4; ++mt)
            af[mt] = *(const short8*)(owb + (size_t)(w * 64 + mt * 16 + ll) * 128 + ko);
        #pragma unroll
        for (int nt = 0; nt < 2; ++nt) {
            short8 bf = *(const short8*)(abase + (size_t)(nt * 16 + ll) * 128 + ko);
            #pragma unroll
            for (int mt = 0; mt < 4; ++mt)
                acc[mt][nt] = __builtin_amdgcn_mfma_f32_16x16x32_bf16(af[mt], bf, acc[mt][nt], 0, 0, 0);
        }
    }

    float gm = gamma[0];
    #pragma unroll
    for (int mt = 0; mt < 4; ++mt)
        #pragma unroll
        for (int nt = 0; nt < 2; ++nt)
            #pragma unroll
            for (int r = 0; r < 4; ++r) {
                int o = w * 64 + mt * 16 + lg * 4 + r;
                size_t oi = ((size_t)(n * 256 + o)) * 4096 + px0 + nt * 16 + ll;
                out[oi] = fmaf(gm, acc[mt][nt][r] + ob[o], x[oi]);
            }
}

extern "C" void kernel_launch(void* const* d_in, const int* in_sizes, int n_in,
                              void* d_out, int out_size, void* d_ws, size_t ws_size,
                              hipStream_t stream) {
    const float* x       = (const float*)d_in[0];
    const float* theta_w = (const float*)d_in[1];
    const float* theta_b = (const float*)d_in[2];
    const float* phi_w   = (const float*)d_in[3];
    const float* phi_b   = (const float*)d_in[4];
    const float* g_w     = (const float*)d_in[5];
    const float* g_b     = (const float*)d_in[6];
    const float* out_w   = (const float*)d_in[7];
    const float* out_b   = (const float*)d_in[8];
    const float* gamma   = (const float*)d_in[9];
    float* out = (float*)d_out;

    char* w8 = (char*)d_ws;
    unsigned short* wb    = (unsigned short*)(w8);               //    98,304 B
    unsigned short* owb   = (unsigned short*)(w8 + 98304);       //    65,536 B
    float*          bcat  = (float*)         (w8 + 163840);      //     1,024 B
    unsigned short* theta = (unsigned short*)(w8 + 164864);      // 2,097,152 B
    unsigned short* phi_t = (unsigned short*)(w8 + 2262016);     //   524,288 B
    unsigned short* g_t   = (unsigned short*)(w8 + 2786304);     // 2,097,152 B
    unsigned short* att_p = (unsigned short*)(w8 + 4883456);     // 8,388,608 B
                                                                 // end ~13.3 MB

    cvt_k<<<321, 256, 0, stream>>>(theta_w, theta_b, phi_w, phi_b, g_w, g_b, out_w,
                                   wb, owb, bcat);
    conv_qkv_k<<<dim3(64, 8), 256, 0, stream>>>(x, wb, bcat, theta, phi_t, g_t);
    attn_k<<<1024, 256, 0, stream>>>(theta, phi_t, g_t, att_p);
    out_mfma_k<<<dim3(128, 8), 256, 0, stream>>>(att_p, owb, out_b, x, gamma, out);
}

// Round 7
// 153.629 us; speedup vs baseline: 24.5965x; 1.2776x over previous
//
#include <hip/hip_runtime.h>
#include <hip/hip_bf16.h>
#include <cstddef>

typedef __attribute__((ext_vector_type(8))) short short8;
typedef __attribute__((ext_vector_type(4))) float f32x4;
typedef __attribute__((ext_vector_type(4))) unsigned int u32x4;
typedef __attribute__((ext_vector_type(2))) unsigned int u32x2;

__device__ __forceinline__ unsigned short f2bf(float f) {
    union { float f; unsigned int u; } v; v.f = f;
    unsigned int r = v.u + 0x7fffu + ((v.u >> 16) & 1u);   // RNE
    return (unsigned short)(r >> 16);
}
__device__ __forceinline__ unsigned int pack2bf(float lo, float hi) {
    __hip_bfloat162 h2 = __float22bfloat162_rn(make_float2(lo, hi));
    union { __hip_bfloat162 h; unsigned int u; } v; v.h = h2;
    return v.u;
}

// ---------- weights/bias -> bf16 concat ----------
__global__ __launch_bounds__(256) void cvt_k(const float* __restrict__ tw,
    const float* __restrict__ tb, const float* __restrict__ pw, const float* __restrict__ pb,
    const float* __restrict__ gw, const float* __restrict__ gb, const float* __restrict__ ow,
    unsigned short* __restrict__ wb, unsigned short* __restrict__ owb, float* __restrict__ bcat)
{
    int idx = blockIdx.x * 256 + threadIdx.x;
    if (idx < 49152) {
        int o = idx >> 8, c = idx & 255;
        float v = (o < 32) ? tw[o * 256 + c] : (o < 64) ? pw[(o - 32) * 256 + c]
                                             : gw[(o - 64) * 256 + c];
        wb[idx] = f2bf(v);
    } else if (idx < 81920) {
        owb[idx - 49152] = f2bf(ow[idx - 49152]);
    } else if (idx < 82112) {
        int o = idx - 81920;
        bcat[o] = (o < 32) ? tb[o] : (o < 64) ? pb[o - 32] : gb[o - 64];
    }
}

// ---------- fused QKV conv GEMM (32-pixel blocks) + maxpool + FRAGMENT-MAJOR scatter ----
// Block: image row-pair rp, col-quarter cq (16 cols). Pixels 0..15 = row 2rp, 16..31 = 2rp+1.
// Outputs: theta (n,i,32); phi_f[n][jtg32][s2][lane64][8]; g_f[n][jtg32][ct8][lane64][8].
__global__ __launch_bounds__(256) void conv_qkv_k(const float* __restrict__ x,
    const unsigned short* __restrict__ wb, const float* __restrict__ bcat,
    unsigned short* __restrict__ theta, unsigned short* __restrict__ phi_f,
    unsigned short* __restrict__ g_f)
{
    __shared__ __align__(16) unsigned int xT[2][32 * 24];   // 32 pixels x (16 data + 8 pad) words
    int bx = blockIdx.x;
    int n  = blockIdx.y;
    int rp = bx >> 2, cq = bx & 3;
    int t = threadIdx.x;
    int w = t >> 6;
    int l = t & 63;
    int lg = l >> 4, ll = l & 15;

    // staging: pixel p = t&31, channel-oct co = t>>5 (4 ch each per 32-chunk)
    int p = t & 31, co = t >> 5;
    int gpix_s = (2 * rp + (p >> 4)) * 64 + cq * 16 + (p & 15);
    const float* xp = x + (size_t)n * 256 * 4096 + gpix_s;

    const f32x4 zero = {0.f, 0.f, 0.f, 0.f};
    f32x4 acc[3][2];
    #pragma unroll
    for (int mt = 0; mt < 3; ++mt)
        #pragma unroll
        for (int nt = 0; nt < 2; ++nt) acc[mt][nt] = zero;

    {   // prologue: stage chunk 0
        float xv[4];
        #pragma unroll
        for (int u = 0; u < 4; ++u) xv[u] = xp[(size_t)(co * 4 + u) * 4096];
        u32x2 pk = {pack2bf(xv[0], xv[1]), pack2bf(xv[2], xv[3])};
        *(u32x2*)&xT[0][p * 24 + co * 2] = pk;
    }
    for (int kk = 0; kk < 8; ++kk) {
        __syncthreads();
        float nv[4];
        if (kk < 7) {
            #pragma unroll
            for (int u = 0; u < 4; ++u)
                nv[u] = xp[(size_t)((kk + 1) * 32 + co * 4 + u) * 4096];
        }
        int ko = kk * 32 + lg * 8;
        short8 af[3];
        #pragma unroll
        for (int mt = 0; mt < 3; ++mt)
            af[mt] = *(const short8*)(wb + (size_t)(w * 48 + mt * 16 + ll) * 256 + ko);
        #pragma unroll
        for (int nt = 0; nt < 2; ++nt) {
            short8 bf = *(const short8*)&xT[kk & 1][(nt * 16 + ll) * 24 + lg * 4];
            #pragma unroll
            for (int mt = 0; mt < 3; ++mt)
                acc[mt][nt] = __builtin_amdgcn_mfma_f32_16x16x32_bf16(af[mt], bf, acc[mt][nt], 0, 0, 0);
        }
        if (kk < 7) {
            u32x2 pk = {pack2bf(nv[0], nv[1]), pack2bf(nv[2], nv[3])};
            *(u32x2*)&xT[(kk + 1) & 1][p * 24 + co * 2] = pk;
        }
    }

    int jj = cq * 8 + (ll >> 1);          // pooled j within row-pair (valid on even ll)
    #pragma unroll
    for (int mt = 0; mt < 3; ++mt) {
        int obase = w * 48 + mt * 16;
        if (obase < 32) {                 // theta: no pool, pack 4 -> 8B store
            #pragma unroll
            for (int nt = 0; nt < 2; ++nt) {
                int gpix = (2 * rp + nt) * 64 + cq * 16 + ll;
                float v0 = acc[mt][nt][0] + bcat[obase + lg * 4 + 0];
                float v1 = acc[mt][nt][1] + bcat[obase + lg * 4 + 1];
                float v2 = acc[mt][nt][2] + bcat[obase + lg * 4 + 2];
                float v3 = acc[mt][nt][3] + bcat[obase + lg * 4 + 3];
                u32x2 pk = {pack2bf(v0, v1), pack2bf(v2, v3)};
                *(u32x2*)&theta[((size_t)(n * 4096 + gpix)) * 32 + obase + lg * 4] = pk;
            }
        } else if (obase < 64) {          // phi: pool -> fragment-major, 8B store
            int d0 = obase - 32;
            float vv[4];
            #pragma unroll
            for (int r = 0; r < 4; ++r) {
                float v = fmaxf(acc[mt][0][r], acc[mt][1][r]);
                vv[r] = fmaxf(v, __shfl_xor(v, 1)) + bcat[obase + lg * 4 + r];
            }
            if (!(ll & 1)) {
                int s = (jj >> 2) & 1;
                int llp = ((jj >> 3) << 2) | (jj & 3);
                int lgp = (d0 >> 3) + (lg >> 1);
                size_t idx = ((((size_t)n * 32 + rp) * 2 + s) * 64 + lgp * 16 + llp) * 8
                           + (lg & 1) * 4;
                u32x2 pk = {pack2bf(vv[0], vv[1]), pack2bf(vv[2], vv[3])};
                *(u32x2*)&phi_f[idx] = pk;
            }
        } else {                          // g: pool -> fragment-major, 2B scatters
            int ct = (obase - 64) >> 4;
            float vv[4];
            #pragma unroll
            for (int r = 0; r < 4; ++r) {
                float v = fmaxf(acc[mt][0][r], acc[mt][1][r]);
                vv[r] = fmaxf(v, __shfl_xor(v, 1)) + bcat[obase + lg * 4 + r];
            }
            if (!(ll & 1)) {
                int lgg = jj >> 3, uu = jj & 7;
                size_t base = ((((size_t)n * 32 + rp) * 8 + ct) * 64 + lgg * 16) * 8 + uu;
                #pragma unroll
                for (int r = 0; r < 4; ++r)
                    g_f[base + (size_t)(lg * 4 + r) * 8] = f2bf(vv[r]);
            }
        }
    }
}

// ---------- flash attention, zero-LDS main loop, fully-coalesced fragment loads ----------
__global__ __launch_bounds__(256, 4) void attn_k(const unsigned short* __restrict__ theta,
    const unsigned short* __restrict__ phi_f, const unsigned short* __restrict__ g_f,
    unsigned short* __restrict__ att_p)
{
    __shared__ float comb[2][64][34];
    int b = blockIdx.x;
    int swz = (b & 7) * 128 + (b >> 3);      // XCD-contiguous (1024 % 8 == 0)
    int n = swz >> 7;
    int i0 = (swz & 127) * 32;
    int t = threadIdx.x;
    int wv = t >> 6;
    int h = wv >> 1, v = wv & 1;
    int l = t & 63;
    int lg = l >> 4, ll = l & 15;
    int i0w = i0 + h * 16;

    short8 bfrag = *(const short8*)(theta + ((size_t)(n * 4096 + i0w + ll)) * 32 + lg * 8);
    const unsigned short* phin = phi_f + (size_t)n * 32768;
    const unsigned short* gfn  = g_f + (size_t)n * 131072;

    const f32x4 zero = {0.f, 0.f, 0.f, 0.f};
    f32x4 acc[8];
    #pragma unroll
    for (int ct = 0; ct < 8; ++ct) acc[ct] = zero;
    float rs = 0.f;

    #pragma unroll 2
    for (int jt = 0; jt < 16; ++jt) {
        int jtg = v * 16 + jt;
        short8 a0 = *(const short8*)(phin + (size_t)jtg * 1024 + l * 8);
        short8 a1 = *(const short8*)(phin + (size_t)jtg * 1024 + 512 + l * 8);
        f32x4 e0 = __builtin_amdgcn_mfma_f32_16x16x32_bf16(a0, bfrag, zero, 0, 0, 0);
        f32x4 e1 = __builtin_amdgcn_mfma_f32_16x16x32_bf16(a1, bfrag, zero, 0, 0, 0);
        float p0[4], p1[4];
        #pragma unroll
        for (int r = 0; r < 4; ++r) {
            p0[r] = __expf(e0[r]); p1[r] = __expf(e1[r]);
            rs += p0[r] + p1[r];
        }
        union { u32x4 u; short8 s; } cv;
        cv.u = (u32x4){pack2bf(p0[0], p0[1]), pack2bf(p0[2], p0[3]),
                       pack2bf(p1[0], p1[1]), pack2bf(p1[2], p1[3])};
        short8 pa = cv.s;
        const unsigned short* gj = gfn + (size_t)jtg * 4096 + l * 8;
        #pragma unroll
        for (int ct = 0; ct < 8; ++ct) {
            short8 gb = *(const short8*)(gj + ct * 512);
            acc[ct] = __builtin_amdgcn_mfma_f32_16x16x32_bf16(pa, gb, acc[ct], 0, 0, 0);
        }
    }

    rs += __shfl_xor(rs, 16);
    rs += __shfl_xor(rs, 32);

    if (v == 1) {
        #pragma unroll
        for (int ct = 0; ct < 8; ++ct)
            #pragma unroll
            for (int r = 0; r < 4; ++r)
                comb[h][l][ct * 4 + r] = acc[ct][r];
        if (lg == 0) comb[h][ll][32] = rs;
    }
    __syncthreads();
    if (v == 0) {
        float inv = 1.f / (rs + comb[h][ll][32]);
        float invr[4];
        #pragma unroll
        for (int r = 0; r < 4; ++r) invr[r] = __shfl(inv, lg * 4 + r);
        #pragma unroll
        for (int ct = 0; ct < 8; ++ct) {
            int c = ct * 16 + ll;
            #pragma unroll
            for (int r = 0; r < 4; ++r) {
                float val = acc[ct][r] + comb[h][l][ct * 4 + r];
                att_p[((size_t)(n * 4096 + i0w + lg * 4 + r)) * 128 + c]
                    = f2bf(val * invr[r]);
            }
        }
    }
}

// ---------- final conv GEMM (M=256, K=128, N=32/block) + gamma*out + x ----------
__global__ __launch_bounds__(256) void out_mfma_k(const unsigned short* __restrict__ att_p,
    const unsigned short* __restrict__ owb, const float* __restrict__ ob,
    const float* __restrict__ x, const float* __restrict__ gamma, float* __restrict__ out)
{
    int px0 = blockIdx.x * 32;
    int n  = blockIdx.y;
    int t = threadIdx.x;
    int w = t >> 6;
    int l = t & 63;
    int lg = l >> 4, ll = l & 15;

    const unsigned short* abase = att_p + ((size_t)(n * 4096 + px0)) * 128;
    const f32x4 zero = {0.f, 0.f, 0.f, 0.f};
    f32x4 acc[4][2];
    #pragma unroll
    for (int mt = 0; mt < 4; ++mt)
        #pragma unroll
        for (int nt = 0; nt < 2; ++nt) acc[mt][nt] = zero;

    #pragma unroll
    for (int kk = 0; kk < 4; ++kk) {
        int ko = kk * 32 + lg * 8;
        short8 af[4];
        #pragma unroll
        for (int mt = 0; mt < 4; ++mt)
            af[mt] = *(const short8*)(owb + (size_t)(w * 64 + mt * 16 + ll) * 128 + ko);
        #pragma unroll
        for (int nt = 0; nt < 2; ++nt) {
            short8 bf = *(const short8*)(abase + (size_t)(nt * 16 + ll) * 128 + ko);
            #pragma unroll
            for (int mt = 0; mt < 4; ++mt)
                acc[mt][nt] = __builtin_amdgcn_mfma_f32_16x16x32_bf16(af[mt], bf, acc[mt][nt], 0, 0, 0);
        }
    }

    float gm = gamma[0];
    #pragma unroll
    for (int mt = 0; mt < 4; ++mt)
        #pragma unroll
        for (int nt = 0; nt < 2; ++nt)
            #pragma unroll
            for (int r = 0; r < 4; ++r) {
                int o = w * 64 + mt * 16 + lg * 4 + r;
                size_t oi = ((size_t)(n * 256 + o)) * 4096 + px0 + nt * 16 + ll;
                out[oi] = fmaf(gm, acc[mt][nt][r] + ob[o], x[oi]);
            }
}

extern "C" void kernel_launch(void* const* d_in, const int* in_sizes, int n_in,
                              void* d_out, int out_size, void* d_ws, size_t ws_size,
                              hipStream_t stream) {
    const float* x       = (const float*)d_in[0];
    const float* theta_w = (const float*)d_in[1];
    const float* theta_b = (const float*)d_in[2];
    const float* phi_w   = (const float*)d_in[3];
    const float* phi_b   = (const float*)d_in[4];
    const float* g_w     = (const float*)d_in[5];
    const float* g_b     = (const float*)d_in[6];
    const float* out_w   = (const float*)d_in[7];
    const float* out_b   = (const float*)d_in[8];
    const float* gamma   = (const float*)d_in[9];
    float* out = (float*)d_out;

    char* w8 = (char*)d_ws;
    unsigned short* wb    = (unsigned short*)(w8);               //    98,304 B
    unsigned short* owb   = (unsigned short*)(w8 + 98304);       //    65,536 B
    float*          bcat  = (float*)         (w8 + 163840);      //     1,024 B
    unsigned short* theta = (unsigned short*)(w8 + 164864);      // 2,097,152 B
    unsigned short* phi_f = (unsigned short*)(w8 + 2262016);     //   524,288 B
    unsigned short* g_f   = (unsigned short*)(w8 + 2786304);     // 2,097,152 B
    unsigned short* att_p = (unsigned short*)(w8 + 4883456);     // 8,388,608 B

    cvt_k<<<321, 256, 0, stream>>>(theta_w, theta_b, phi_w, phi_b, g_w, g_b, out_w,
                                   wb, owb, bcat);
    conv_qkv_k<<<dim3(128, 8), 256, 0, stream>>>(x, wb, bcat, theta, phi_f, g_f);
    attn_k<<<1024, 256, 0, stream>>>(theta, phi_f, g_f, att_p);
    out_mfma_k<<<dim3(128, 8), 256, 0, stream>>>(att_p, owb, out_b, x, gamma, out);
}

// Round 8
// 139.125 us; speedup vs baseline: 27.1606x; 1.1043x over previous
//
#include <hip/hip_runtime.h>
#include <hip/hip_bf16.h>
#include <cstddef>

typedef __attribute__((ext_vector_type(8))) short short8;
typedef __attribute__((ext_vector_type(4))) float f32x4;
typedef __attribute__((ext_vector_type(4))) unsigned int u32x4;
typedef __attribute__((ext_vector_type(2))) unsigned int u32x2;

__device__ __forceinline__ unsigned short f2bf(float f) {
    union { float f; unsigned int u; } v; v.f = f;
    unsigned int r = v.u + 0x7fffu + ((v.u >> 16) & 1u);   // RNE
    return (unsigned short)(r >> 16);
}
__device__ __forceinline__ unsigned int pack2bf(float lo, float hi) {
    __hip_bfloat162 h2 = __float22bfloat162_rn(make_float2(lo, hi));
    union { __hip_bfloat162 h; unsigned int u; } v; v.h = h2;
    return v.u;
}

// ---------- weights/bias -> bf16; out_w scattered FRAGMENT-MAJOR ----------
// owf[w4][mt4][kk4][lane64][8]: value = ow[o=w*64+mt*16+ll][c=kk*32+lg*8+u]
__global__ __launch_bounds__(256) void cvt_k(const float* __restrict__ tw,
    const float* __restrict__ tb, const float* __restrict__ pw, const float* __restrict__ pb,
    const float* __restrict__ gw, const float* __restrict__ gb, const float* __restrict__ ow,
    unsigned short* __restrict__ wb, unsigned short* __restrict__ owf, float* __restrict__ bcat)
{
    int idx = blockIdx.x * 256 + threadIdx.x;
    if (idx < 49152) {
        int o = idx >> 8, c = idx & 255;
        float v = (o < 32) ? tw[o * 256 + c] : (o < 64) ? pw[(o - 32) * 256 + c]
                                             : gw[(o - 64) * 256 + c];
        wb[idx] = f2bf(v);
    } else if (idx < 81920) {
        int i2 = idx - 49152;                 // o*128 + c
        int o = i2 >> 7, c = i2 & 127;
        int w = o >> 6, mt = (o >> 4) & 3, llp = o & 15;
        int kk = c >> 5, lg = (c >> 3) & 3, u = c & 7;
        size_t pos = ((((size_t)(w * 4 + mt) * 4 + kk) * 64) + lg * 16 + llp) * 8 + u;
        owf[pos] = f2bf(ow[i2]);
    } else if (idx < 82112) {
        int o = idx - 81920;
        bcat[o] = (o < 32) ? tb[o] : (o < 64) ? pb[o - 32] : gb[o - 64];
    }
}

// ---------- fused QKV conv GEMM (32-pixel blocks) + maxpool + FRAGMENT-MAJOR scatter ----
__global__ __launch_bounds__(256) void conv_qkv_k(const float* __restrict__ x,
    const unsigned short* __restrict__ wb, const float* __restrict__ bcat,
    unsigned short* __restrict__ theta, unsigned short* __restrict__ phi_f,
    unsigned short* __restrict__ g_f)
{
    __shared__ __align__(16) unsigned int xT[2][32 * 24];
    int bx = blockIdx.x;
    int n  = blockIdx.y;
    int rp = bx >> 2, cq = bx & 3;
    int t = threadIdx.x;
    int w = t >> 6;
    int l = t & 63;
    int lg = l >> 4, ll = l & 15;

    int p = t & 31, co = t >> 5;
    int gpix_s = (2 * rp + (p >> 4)) * 64 + cq * 16 + (p & 15);
    const float* xp = x + (size_t)n * 256 * 4096 + gpix_s;

    const f32x4 zero = {0.f, 0.f, 0.f, 0.f};
    f32x4 acc[3][2];
    #pragma unroll
    for (int mt = 0; mt < 3; ++mt)
        #pragma unroll
        for (int nt = 0; nt < 2; ++nt) acc[mt][nt] = zero;

    {
        float xv[4];
        #pragma unroll
        for (int u = 0; u < 4; ++u) xv[u] = xp[(size_t)(co * 4 + u) * 4096];
        u32x2 pk = {pack2bf(xv[0], xv[1]), pack2bf(xv[2], xv[3])};
        *(u32x2*)&xT[0][p * 24 + co * 2] = pk;
    }
    for (int kk = 0; kk < 8; ++kk) {
        __syncthreads();
        float nv[4];
        if (kk < 7) {
            #pragma unroll
            for (int u = 0; u < 4; ++u)
                nv[u] = xp[(size_t)((kk + 1) * 32 + co * 4 + u) * 4096];
        }
        int ko = kk * 32 + lg * 8;
        short8 af[3];
        #pragma unroll
        for (int mt = 0; mt < 3; ++mt)
            af[mt] = *(const short8*)(wb + (size_t)(w * 48 + mt * 16 + ll) * 256 + ko);
        #pragma unroll
        for (int nt = 0; nt < 2; ++nt) {
            short8 bf = *(const short8*)&xT[kk & 1][(nt * 16 + ll) * 24 + lg * 4];
            #pragma unroll
            for (int mt = 0; mt < 3; ++mt)
                acc[mt][nt] = __builtin_amdgcn_mfma_f32_16x16x32_bf16(af[mt], bf, acc[mt][nt], 0, 0, 0);
        }
        if (kk < 7) {
            u32x2 pk = {pack2bf(nv[0], nv[1]), pack2bf(nv[2], nv[3])};
            *(u32x2*)&xT[(kk + 1) & 1][p * 24 + co * 2] = pk;
        }
    }

    int jj = cq * 8 + (ll >> 1);
    #pragma unroll
    for (int mt = 0; mt < 3; ++mt) {
        int obase = w * 48 + mt * 16;
        if (obase < 32) {
            #pragma unroll
            for (int nt = 0; nt < 2; ++nt) {
                int gpix = (2 * rp + nt) * 64 + cq * 16 + ll;
                float v0 = acc[mt][nt][0] + bcat[obase + lg * 4 + 0];
                float v1 = acc[mt][nt][1] + bcat[obase + lg * 4 + 1];
                float v2 = acc[mt][nt][2] + bcat[obase + lg * 4 + 2];
                float v3 = acc[mt][nt][3] + bcat[obase + lg * 4 + 3];
                u32x2 pk = {pack2bf(v0, v1), pack2bf(v2, v3)};
                *(u32x2*)&theta[((size_t)(n * 4096 + gpix)) * 32 + obase + lg * 4] = pk;
            }
        } else if (obase < 64) {
            int d0 = obase - 32;
            float vv[4];
            #pragma unroll
            for (int r = 0; r < 4; ++r) {
                float v = fmaxf(acc[mt][0][r], acc[mt][1][r]);
                vv[r] = fmaxf(v, __shfl_xor(v, 1)) + bcat[obase + lg * 4 + r];
            }
            if (!(ll & 1)) {
                int s = (jj >> 2) & 1;
                int llp = ((jj >> 3) << 2) | (jj & 3);
                int lgp = (d0 >> 3) + (lg >> 1);
                size_t idx = ((((size_t)n * 32 + rp) * 2 + s) * 64 + lgp * 16 + llp) * 8
                           + (lg & 1) * 4;
                u32x2 pk = {pack2bf(vv[0], vv[1]), pack2bf(vv[2], vv[3])};
                *(u32x2*)&phi_f[idx] = pk;
            }
        } else {
            int ct = (obase - 64) >> 4;
            float vv[4];
            #pragma unroll
            for (int r = 0; r < 4; ++r) {
                float v = fmaxf(acc[mt][0][r], acc[mt][1][r]);
                vv[r] = fmaxf(v, __shfl_xor(v, 1)) + bcat[obase + lg * 4 + r];
            }
            if (!(ll & 1)) {
                int lgg = jj >> 3, uu = jj & 7;
                size_t base = ((((size_t)n * 32 + rp) * 8 + ct) * 64 + lgg * 16) * 8 + uu;
                #pragma unroll
                for (int r = 0; r < 4; ++r)
                    g_f[base + (size_t)(lg * 4 + r) * 8] = f2bf(vv[r]);
            }
        }
    }
}

// ---------- flash attention + FUSED final conv + residual ----------
// Phase 1: zero-LDS QK^T/exp/PV (fragment-major coalesced loads).
// Phase 2: cross-wave combine (LDS).  Phase 3: normalized att -> att_lds bf16.
// Phase 4: out GEMM (M=256,N=32,K=128), owf fragment-major.  Phase 5: gamma*.+x.
__global__ __launch_bounds__(256, 4) void attn_out_k(const unsigned short* __restrict__ theta,
    const unsigned short* __restrict__ phi_f, const unsigned short* __restrict__ g_f,
    const unsigned short* __restrict__ owf, const float* __restrict__ ob,
    const float* __restrict__ x, const float* __restrict__ gamma, float* __restrict__ out)
{
    __shared__ float comb[2][64][34];                       // 17408 B
    __shared__ __align__(16) unsigned short att_lds[32][136]; // 8704 B (stride 272B)
    int b = blockIdx.x;
    int swz = (b & 7) * 128 + (b >> 3);      // XCD-contiguous (1024 % 8 == 0)
    int n = swz >> 7;
    int i0 = (swz & 127) * 32;
    int t = threadIdx.x;
    int wv = t >> 6;
    int h = wv >> 1, v = wv & 1;
    int l = t & 63;
    int lg = l >> 4, ll = l & 15;
    int i0w = i0 + h * 16;

    short8 bfrag = *(const short8*)(theta + ((size_t)(n * 4096 + i0w + ll)) * 32 + lg * 8);
    const unsigned short* phin = phi_f + (size_t)n * 32768;
    const unsigned short* gfn  = g_f + (size_t)n * 131072;

    const f32x4 zero = {0.f, 0.f, 0.f, 0.f};
    f32x4 acc[8];
    #pragma unroll
    for (int ct = 0; ct < 8; ++ct) acc[ct] = zero;
    float rs = 0.f;

    #pragma unroll 2
    for (int jt = 0; jt < 16; ++jt) {
        int jtg = v * 16 + jt;
        short8 a0 = *(const short8*)(phin + (size_t)jtg * 1024 + l * 8);
        short8 a1 = *(const short8*)(phin + (size_t)jtg * 1024 + 512 + l * 8);
        f32x4 e0 = __builtin_amdgcn_mfma_f32_16x16x32_bf16(a0, bfrag, zero, 0, 0, 0);
        f32x4 e1 = __builtin_amdgcn_mfma_f32_16x16x32_bf16(a1, bfrag, zero, 0, 0, 0);
        float p0[4], p1[4];
        #pragma unroll
        for (int r = 0; r < 4; ++r) {
            p0[r] = __expf(e0[r]); p1[r] = __expf(e1[r]);
            rs += p0[r] + p1[r];
        }
        union { u32x4 u; short8 s; } cv;
        cv.u = (u32x4){pack2bf(p0[0], p0[1]), pack2bf(p0[2], p0[3]),
                       pack2bf(p1[0], p1[1]), pack2bf(p1[2], p1[3])};
        short8 pa = cv.s;
        const unsigned short* gj = gfn + (size_t)jtg * 4096 + l * 8;
        #pragma unroll
        for (int ct = 0; ct < 8; ++ct) {
            short8 gb = *(const short8*)(gj + ct * 512);
            acc[ct] = __builtin_amdgcn_mfma_f32_16x16x32_bf16(pa, gb, acc[ct], 0, 0, 0);
        }
    }

    rs += __shfl_xor(rs, 16);
    rs += __shfl_xor(rs, 32);

    if (v == 1) {
        #pragma unroll
        for (int ct = 0; ct < 8; ++ct)
            #pragma unroll
            for (int r = 0; r < 4; ++r)
                comb[h][l][ct * 4 + r] = acc[ct][r];
        if (lg == 0) comb[h][ll][32] = rs;
    }
    __syncthreads();
    if (v == 0) {
        float inv = 1.f / (rs + comb[h][ll][32]);
        float invr[4];
        #pragma unroll
        for (int r = 0; r < 4; ++r) invr[r] = __shfl(inv, lg * 4 + r);
        #pragma unroll
        for (int ct = 0; ct < 8; ++ct) {
            int c = ct * 16 + ll;
            #pragma unroll
            for (int r = 0; r < 4; ++r) {
                float val = acc[ct][r] + comb[h][l][ct * 4 + r];
                att_lds[h * 16 + lg * 4 + r][c] = f2bf(val * invr[r]);
            }
        }
    }
    __syncthreads();

    // ---- Phase 4: out GEMM. wave wv handles o in [wv*64, wv*64+64) ----
    f32x4 acc2[4][2];
    #pragma unroll
    for (int mt = 0; mt < 4; ++mt)
        #pragma unroll
        for (int nt = 0; nt < 2; ++nt) acc2[mt][nt] = zero;

    #pragma unroll
    for (int kk = 0; kk < 4; ++kk) {
        short8 af[4];
        #pragma unroll
        for (int mt = 0; mt < 4; ++mt)
            af[mt] = *(const short8*)(owf
                + ((((size_t)(wv * 4 + mt) * 4 + kk) * 64) + l) * 8);
        #pragma unroll
        for (int nt = 0; nt < 2; ++nt) {
            short8 bf = *(const short8*)&att_lds[nt * 16 + ll][kk * 32 + lg * 8];
            #pragma unroll
            for (int mt = 0; mt < 4; ++mt)
                acc2[mt][nt] = __builtin_amdgcn_mfma_f32_16x16x32_bf16(af[mt], bf, acc2[mt][nt], 0, 0, 0);
        }
    }

    float gm = gamma[0];
    #pragma unroll
    for (int mt = 0; mt < 4; ++mt)
        #pragma unroll
        for (int nt = 0; nt < 2; ++nt)
            #pragma unroll
            for (int r = 0; r < 4; ++r) {
                int o = wv * 64 + mt * 16 + lg * 4 + r;
                size_t oi = ((size_t)(n * 256 + o)) * 4096 + i0 + nt * 16 + ll;
                out[oi] = fmaf(gm, acc2[mt][nt][r] + ob[o], x[oi]);
            }
}

extern "C" void kernel_launch(void* const* d_in, const int* in_sizes, int n_in,
                              void* d_out, int out_size, void* d_ws, size_t ws_size,
                              hipStream_t stream) {
    const float* x       = (const float*)d_in[0];
    const float* theta_w = (const float*)d_in[1];
    const float* theta_b = (const float*)d_in[2];
    const float* phi_w   = (const float*)d_in[3];
    const float* phi_b   = (const float*)d_in[4];
    const float* g_w     = (const float*)d_in[5];
    const float* g_b     = (const float*)d_in[6];
    const float* out_w   = (const float*)d_in[7];
    const float* out_b   = (const float*)d_in[8];
    const float* gamma   = (const float*)d_in[9];
    float* out = (float*)d_out;

    char* w8 = (char*)d_ws;
    unsigned short* wb    = (unsigned short*)(w8);               //    98,304 B
    unsigned short* owf   = (unsigned short*)(w8 + 98304);       //    65,536 B
    float*          bcat  = (float*)         (w8 + 163840);      //     1,024 B
    unsigned short* theta = (unsigned short*)(w8 + 164864);      // 2,097,152 B
    unsigned short* phi_f = (unsigned short*)(w8 + 2262016);     //   524,288 B
    unsigned short* g_f   = (unsigned short*)(w8 + 2786304);     // 2,097,152 B
                                                                 // end ~4.9 MB

    cvt_k<<<321, 256, 0, stream>>>(theta_w, theta_b, phi_w, phi_b, g_w, g_b, out_w,
                                   wb, owf, bcat);
    conv_qkv_k<<<dim3(128, 8), 256, 0, stream>>>(x, wb, bcat, theta, phi_f, g_f);
    attn_out_k<<<1024, 256, 0, stream>>>(theta, phi_f, g_f, owf, out_b, x, gamma, out);
}

// Round 9
// 138.176 us; speedup vs baseline: 27.3473x; 1.0069x over previous
//
#include <hip/hip_runtime.h>
#include <hip/hip_bf16.h>
#include <cstddef>

typedef __attribute__((ext_vector_type(8))) short short8;
typedef __attribute__((ext_vector_type(4))) float f32x4;
typedef __attribute__((ext_vector_type(4))) unsigned int u32x4;
typedef __attribute__((ext_vector_type(2))) unsigned int u32x2;

__device__ __forceinline__ unsigned short f2bf(float f) {
    union { float f; unsigned int u; } v; v.f = f;
    unsigned int r = v.u + 0x7fffu + ((v.u >> 16) & 1u);   // RNE
    return (unsigned short)(r >> 16);
}
__device__ __forceinline__ unsigned int pack2bf(float lo, float hi) {
    __hip_bfloat162 h2 = __float22bfloat162_rn(make_float2(lo, hi));
    union { __hip_bfloat162 h; unsigned int u; } v; v.h = h2;
    return v.u;
}

// ---------- weights/bias -> bf16; out_w scattered FRAGMENT-MAJOR ----------
__global__ __launch_bounds__(256) void cvt_k(const float* __restrict__ tw,
    const float* __restrict__ tb, const float* __restrict__ pw, const float* __restrict__ pb,
    const float* __restrict__ gw, const float* __restrict__ gb, const float* __restrict__ ow,
    unsigned short* __restrict__ wb, unsigned short* __restrict__ owf, float* __restrict__ bcat)
{
    int idx = blockIdx.x * 256 + threadIdx.x;
    if (idx < 49152) {
        int o = idx >> 8, c = idx & 255;
        float v = (o < 32) ? tw[o * 256 + c] : (o < 64) ? pw[(o - 32) * 256 + c]
                                             : gw[(o - 64) * 256 + c];
        wb[idx] = f2bf(v);
    } else if (idx < 81920) {
        int i2 = idx - 49152;                 // o*128 + c
        int o = i2 >> 7, c = i2 & 127;
        int w = o >> 6, mt = (o >> 4) & 3, llp = o & 15;
        int kk = c >> 5, lg = (c >> 3) & 3, u = c & 7;
        size_t pos = ((((size_t)(w * 4 + mt) * 4 + kk) * 64) + lg * 16 + llp) * 8 + u;
        owf[pos] = f2bf(ow[i2]);
    } else if (idx < 82112) {
        int o = idx - 81920;
        bcat[o] = (o < 32) ? tb[o] : (o < 64) ? pb[o - 32] : gb[o - 64];
    }
}

// ---------- fused QKV conv GEMM (32-pixel blocks), float4 staging + XOR-swizzled LDS ----
// LDS tile: row = local pixel (32), 24 dwords/row; dword col' = (ch>>1) ^ (((px>>2)&3)<<2).
// Writes: 2-way bank max (free); b128 frag reads 16B-aligned, bank-uniform.
__global__ __launch_bounds__(256) void conv_qkv_k(const float* __restrict__ x,
    const unsigned short* __restrict__ wb, const float* __restrict__ bcat,
    unsigned short* __restrict__ theta, unsigned short* __restrict__ phi_f,
    unsigned short* __restrict__ g_f)
{
    __shared__ __align__(16) unsigned int xT[2][32 * 24];   // 6 KB
    int bx = blockIdx.x;
    int n  = blockIdx.y;
    int rp = bx >> 2, cq = bx & 3;
    int t = threadIdx.x;
    int w = t >> 6;
    int l = t & 63;
    int lg = l >> 4, ll = l & 15;

    // staging ids: ch = t>>3 (0..31), q = t&7 -> pixel quad
    int ch = t >> 3, q = t & 7;
    int prow = (q >> 2) * 16 + (q & 3) * 4;                 // local px of quad start
    int gpix_q = (2 * rp + (q >> 2)) * 64 + cq * 16 + (q & 3) * 4;
    const float* xp4 = x + (size_t)n * 256 * 4096 + gpix_q;
    // writer dword columns for the 4 pixels of the quad (XOR-swizzle; (px>>2)&3 == q&3)
    int wcol = (ch >> 1) ^ ((q & 3) << 2);
    int wbyte = ch & 1;

    const f32x4 zero = {0.f, 0.f, 0.f, 0.f};
    f32x4 acc[3][2];
    #pragma unroll
    for (int mt = 0; mt < 3; ++mt)
        #pragma unroll
        for (int nt = 0; nt < 2; ++nt) acc[mt][nt] = zero;

    {   // prologue: stage chunk 0
        float4 xv = *(const float4*)(xp4 + (size_t)ch * 4096);
        unsigned short* r0 = (unsigned short*)&xT[0][(prow + 0) * 24 + wcol];
        unsigned short* r1 = (unsigned short*)&xT[0][(prow + 1) * 24 + wcol];
        unsigned short* r2 = (unsigned short*)&xT[0][(prow + 2) * 24 + wcol];
        unsigned short* r3 = (unsigned short*)&xT[0][(prow + 3) * 24 + wcol];
        r0[wbyte] = f2bf(xv.x); r1[wbyte] = f2bf(xv.y);
        r2[wbyte] = f2bf(xv.z); r3[wbyte] = f2bf(xv.w);
    }
    for (int kk = 0; kk < 8; ++kk) {
        __syncthreads();
        float4 nv;
        if (kk < 7)
            nv = *(const float4*)(xp4 + (size_t)((kk + 1) * 32 + ch) * 4096);
        int ko = kk * 32 + lg * 8;
        short8 af[3];
        #pragma unroll
        for (int mt = 0; mt < 3; ++mt)
            af[mt] = *(const short8*)(wb + (size_t)(w * 48 + mt * 16 + ll) * 256 + ko);
        #pragma unroll
        for (int nt = 0; nt < 2; ++nt) {
            short8 bf = *(const short8*)&xT[kk & 1][(nt * 16 + ll) * 24 + ((lg ^ (ll >> 2)) << 2)];
            #pragma unroll
            for (int mt = 0; mt < 3; ++mt)
                acc[mt][nt] = __builtin_amdgcn_mfma_f32_16x16x32_bf16(af[mt], bf, acc[mt][nt], 0, 0, 0);
        }
        if (kk < 7) {
            int bsel = (kk + 1) & 1;
            unsigned short* r0 = (unsigned short*)&xT[bsel][(prow + 0) * 24 + wcol];
            unsigned short* r1 = (unsigned short*)&xT[bsel][(prow + 1) * 24 + wcol];
            unsigned short* r2 = (unsigned short*)&xT[bsel][(prow + 2) * 24 + wcol];
            unsigned short* r3 = (unsigned short*)&xT[bsel][(prow + 3) * 24 + wcol];
            r0[wbyte] = f2bf(nv.x); r1[wbyte] = f2bf(nv.y);
            r2[wbyte] = f2bf(nv.z); r3[wbyte] = f2bf(nv.w);
        }
    }

    int jj = cq * 8 + (ll >> 1);
    #pragma unroll
    for (int mt = 0; mt < 3; ++mt) {
        int obase = w * 48 + mt * 16;
        if (obase < 32) {
            #pragma unroll
            for (int nt = 0; nt < 2; ++nt) {
                int gpix = (2 * rp + nt) * 64 + cq * 16 + ll;
                float v0 = acc[mt][nt][0] + bcat[obase + lg * 4 + 0];
                float v1 = acc[mt][nt][1] + bcat[obase + lg * 4 + 1];
                float v2 = acc[mt][nt][2] + bcat[obase + lg * 4 + 2];
                float v3 = acc[mt][nt][3] + bcat[obase + lg * 4 + 3];
                u32x2 pk = {pack2bf(v0, v1), pack2bf(v2, v3)};
                *(u32x2*)&theta[((size_t)(n * 4096 + gpix)) * 32 + obase + lg * 4] = pk;
            }
        } else if (obase < 64) {
            int d0 = obase - 32;
            float vv[4];
            #pragma unroll
            for (int r = 0; r < 4; ++r) {
                float v = fmaxf(acc[mt][0][r], acc[mt][1][r]);
                vv[r] = fmaxf(v, __shfl_xor(v, 1)) + bcat[obase + lg * 4 + r];
            }
            if (!(ll & 1)) {
                int s = (jj >> 2) & 1;
                int llp = ((jj >> 3) << 2) | (jj & 3);
                int lgp = (d0 >> 3) + (lg >> 1);
                size_t idx = ((((size_t)n * 32 + rp) * 2 + s) * 64 + lgp * 16 + llp) * 8
                           + (lg & 1) * 4;
                u32x2 pk = {pack2bf(vv[0], vv[1]), pack2bf(vv[2], vv[3])};
                *(u32x2*)&phi_f[idx] = pk;
            }
        } else {
            int ct = (obase - 64) >> 4;
            float vv[4];
            #pragma unroll
            for (int r = 0; r < 4; ++r) {
                float v = fmaxf(acc[mt][0][r], acc[mt][1][r]);
                vv[r] = fmaxf(v, __shfl_xor(v, 1)) + bcat[obase + lg * 4 + r];
            }
            if (!(ll & 1)) {
                int lgg = jj >> 3, uu = jj & 7;
                size_t base = ((((size_t)n * 32 + rp) * 8 + ct) * 64 + lgg * 16) * 8 + uu;
                #pragma unroll
                for (int r = 0; r < 4; ++r)
                    g_f[base + (size_t)(lg * 4 + r) * 8] = f2bf(vv[r]);
            }
        }
    }
}

// ---------- flash attention + FUSED final conv + residual ----------
__global__ __launch_bounds__(256, 4) void attn_out_k(const unsigned short* __restrict__ theta,
    const unsigned short* __restrict__ phi_f, const unsigned short* __restrict__ g_f,
    const unsigned short* __restrict__ owf, const float* __restrict__ ob,
    const float* __restrict__ x, const float* __restrict__ gamma, float* __restrict__ out)
{
    __shared__ float comb[2][64][34];                         // 17408 B
    __shared__ __align__(16) unsigned short att_lds[32][136]; // 8704 B
    int b = blockIdx.x;
    int swz = (b & 7) * 128 + (b >> 3);      // XCD-contiguous (1024 % 8 == 0)
    int n = swz >> 7;
    int i0 = (swz & 127) * 32;
    int t = threadIdx.x;
    int wv = t >> 6;
    int h = wv >> 1, v = wv & 1;
    int l = t & 63;
    int lg = l >> 4, ll = l & 15;
    int i0w = i0 + h * 16;

    short8 bfrag = *(const short8*)(theta + ((size_t)(n * 4096 + i0w + ll)) * 32 + lg * 8);
    const unsigned short* phin = phi_f + (size_t)n * 32768;
    const unsigned short* gfn  = g_f + (size_t)n * 131072;

    const f32x4 zero = {0.f, 0.f, 0.f, 0.f};
    f32x4 acc[8];
    #pragma unroll
    for (int ct = 0; ct < 8; ++ct) acc[ct] = zero;
    float rs = 0.f;

    #pragma unroll 2
    for (int jt = 0; jt < 16; ++jt) {
        int jtg = v * 16 + jt;
        short8 a0 = *(const short8*)(phin + (size_t)jtg * 1024 + l * 8);
        short8 a1 = *(const short8*)(phin + (size_t)jtg * 1024 + 512 + l * 8);
        f32x4 e0 = __builtin_amdgcn_mfma_f32_16x16x32_bf16(a0, bfrag, zero, 0, 0, 0);
        f32x4 e1 = __builtin_amdgcn_mfma_f32_16x16x32_bf16(a1, bfrag, zero, 0, 0, 0);
        float p0[4], p1[4];
        #pragma unroll
        for (int r = 0; r < 4; ++r) {
            p0[r] = __expf(e0[r]); p1[r] = __expf(e1[r]);
            rs += p0[r] + p1[r];
        }
        union { u32x4 u; short8 s; } cv;
        cv.u = (u32x4){pack2bf(p0[0], p0[1]), pack2bf(p0[2], p0[3]),
                       pack2bf(p1[0], p1[1]), pack2bf(p1[2], p1[3])};
        short8 pa = cv.s;
        const unsigned short* gj = gfn + (size_t)jtg * 4096 + l * 8;
        #pragma unroll
        for (int ct = 0; ct < 8; ++ct) {
            short8 gb = *(const short8*)(gj + ct * 512);
            acc[ct] = __builtin_amdgcn_mfma_f32_16x16x32_bf16(pa, gb, acc[ct], 0, 0, 0);
        }
    }

    rs += __shfl_xor(rs, 16);
    rs += __shfl_xor(rs, 32);

    if (v == 1) {
        #pragma unroll
        for (int ct = 0; ct < 8; ++ct)
            #pragma unroll
            for (int r = 0; r < 4; ++r)
                comb[h][l][ct * 4 + r] = acc[ct][r];
        if (lg == 0) comb[h][ll][32] = rs;
    }
    __syncthreads();
    if (v == 0) {
        float inv = 1.f / (rs + comb[h][ll][32]);
        float invr[4];
        #pragma unroll
        for (int r = 0; r < 4; ++r) invr[r] = __shfl(inv, lg * 4 + r);
        #pragma unroll
        for (int ct = 0; ct < 8; ++ct) {
            int c = ct * 16 + ll;
            #pragma unroll
            for (int r = 0; r < 4; ++r) {
                float val = acc[ct][r] + comb[h][l][ct * 4 + r];
                att_lds[h * 16 + lg * 4 + r][c] = f2bf(val * invr[r]);
            }
        }
    }
    __syncthreads();

    // ---- out GEMM: wave wv handles o in [wv*64, wv*64+64) ----
    f32x4 acc2[4][2];
    #pragma unroll
    for (int mt = 0; mt < 4; ++mt)
        #pragma unroll
        for (int nt = 0; nt < 2; ++nt) acc2[mt][nt] = zero;

    #pragma unroll
    for (int kk = 0; kk < 4; ++kk) {
        short8 af[4];
        #pragma unroll
        for (int mt = 0; mt < 4; ++mt)
            af[mt] = *(const short8*)(owf
                + ((((size_t)(wv * 4 + mt) * 4 + kk) * 64) + l) * 8);
        #pragma unroll
        for (int nt = 0; nt < 2; ++nt) {
            short8 bf = *(const short8*)&att_lds[nt * 16 + ll][kk * 32 + lg * 8];
            #pragma unroll
            for (int mt = 0; mt < 4; ++mt)
                acc2[mt][nt] = __builtin_amdgcn_mfma_f32_16x16x32_bf16(af[mt], bf, acc2[mt][nt], 0, 0, 0);
        }
    }

    float gm = gamma[0];
    #pragma unroll
    for (int mt = 0; mt < 4; ++mt)
        #pragma unroll
        for (int nt = 0; nt < 2; ++nt)
            #pragma unroll
            for (int r = 0; r < 4; ++r) {
                int o = wv * 64 + mt * 16 + lg * 4 + r;
                size_t oi = ((size_t)(n * 256 + o)) * 4096 + i0 + nt * 16 + ll;
                out[oi] = fmaf(gm, acc2[mt][nt][r] + ob[o], x[oi]);
            }
}

extern "C" void kernel_launch(void* const* d_in, const int* in_sizes, int n_in,
                              void* d_out, int out_size, void* d_ws, size_t ws_size,
                              hipStream_t stream) {
    const float* x       = (const float*)d_in[0];
    const float* theta_w = (const float*)d_in[1];
    const float* theta_b = (const float*)d_in[2];
    const float* phi_w   = (const float*)d_in[3];
    const float* phi_b   = (const float*)d_in[4];
    const float* g_w     = (const float*)d_in[5];
    const float* g_b     = (const float*)d_in[6];
    const float* out_w   = (const float*)d_in[7];
    const float* out_b   = (const float*)d_in[8];
    const float* gamma   = (const float*)d_in[9];
    float* out = (float*)d_out;

    char* w8 = (char*)d_ws;
    unsigned short* wb    = (unsigned short*)(w8);               //    98,304 B
    unsigned short* owf   = (unsigned short*)(w8 + 98304);       //    65,536 B
    float*          bcat  = (float*)         (w8 + 163840);      //     1,024 B
    unsigned short* theta = (unsigned short*)(w8 + 164864);      // 2,097,152 B
    unsigned short* phi_f = (unsigned short*)(w8 + 2262016);     //   524,288 B
    unsigned short* g_f   = (unsigned short*)(w8 + 2786304);     // 2,097,152 B

    cvt_k<<<321, 256, 0, stream>>>(theta_w, theta_b, phi_w, phi_b, g_w, g_b, out_w,
                                   wb, owf, bcat);
    conv_qkv_k<<<dim3(128, 8), 256, 0, stream>>>(x, wb, bcat, theta, phi_f, g_f);
    attn_out_k<<<1024, 256, 0, stream>>>(theta, phi_f, g_f, owf, out_b, x, gamma, out);
}